// Round 10
// baseline (510.976 us; speedup 1.0000x reference)
//
#include <hip/hip_runtime.h>
#include <cmath>

// Problem constants
#define Bb 256
#define Ss 50
#define Cc 40
#define Dd 256
#define Vv 20000

typedef __bf16 bf16;
typedef __bf16 bf16x8 __attribute__((ext_vector_type(8)));
typedef float f32x4 __attribute__((ext_vector_type(4)));
typedef unsigned long long u64;

#define GL2LDS(g, l) __builtin_amdgcn_global_load_lds( \
    (__attribute__((address_space(1))) void*)(g), \
    (__attribute__((address_space(3))) void*)(l), 16, 0, 0)

// ---------------- ws layout (BYTE offsets) ----------------
#define OFFB_GATES    0ull
#define OFFB_ALIGNED  0ull
#define OFFB_WBB      13107200ull
#define OFFB_TMPB     25952256ull
#define OFFB_H1       32505856ull
#define OFFB_X        52428800ull
#define OFFB_XB       65536000ull
#define OFFB_RNNB     72089600ull
#define OFFB_W        78643200ull
#define OFFB_BAR      91750400ull
#define OFFB_WIHB     92012544ull
#define OFFB_WHHB     92536832ull
#define OFFB_WHKB     93061120ull
#define OFFB_W1B      93192192ull
#define OFFB_WDTB     93257728ull
#define OFFB_SALPHA   93388800ull
#define OFFB_SBETA    93389824ull

// ---------------- bf16 MFMA GEMM (optional extra bf16 output Cb) ----------
template<int BM, int BN, int ACT>
__global__ __launch_bounds__(256) void mfma_gemm(
    const bf16* __restrict__ A, int lda,
    const bf16* __restrict__ B, int ldb,
    const float* __restrict__ bias1, const float* __restrict__ bias2,
    float* __restrict__ C, bf16* __restrict__ Cb, int ldc, int K)
{
    constexpr int BK = 32;
    constexpr int NF = BN / 32;           // n-frags per wave (2x2 wave grid)
    __shared__ bf16 As[BM * BK];
    __shared__ bf16 Bs[BN * BK];
    const int tid  = threadIdx.x;
    const int wave = tid >> 6;
    const int lane = tid & 63;
    const int m0 = blockIdx.x * BM;
    const int n0 = blockIdx.y * BN;
    const int wm = (wave >> 1) * 64;      // wave row offset in tile
    const int wn = (wave & 1) * (BN / 2); // wave col offset in tile

    f32x4 acc[4][NF];
#pragma unroll
    for (int i = 0; i < 4; ++i)
#pragma unroll
        for (int j = 0; j < NF; ++j) acc[i][j] = (f32x4){0.f, 0.f, 0.f, 0.f};

    const int ar = tid >> 2;              // staging row (0..63) within iter
    const int ac = tid & 3;               // staging chunk
    const int sw = ac ^ (ar & 3);         // swizzled source chunk
    const int lr = lane & 15;
    const int q  = lane >> 4;             // k-chunk of fragment

    for (int k0 = 0; k0 < K; k0 += BK) {
        __syncthreads();
#pragma unroll
        for (int it = 0; it < BM / 64; ++it) {
            const bf16* gp = A + (size_t)(m0 + it * 64 + ar) * lda + k0 + sw * 8;
            GL2LDS(gp, As + it * 2048 + wave * 512);
        }
#pragma unroll
        for (int it = 0; it < BN / 64; ++it) {
            const bf16* gp = B + (size_t)(n0 + it * 64 + ar) * ldb + k0 + sw * 8;
            GL2LDS(gp, Bs + it * 2048 + wave * 512);
        }
        __syncthreads();

        bf16x8 af[4], bfv[NF];
#pragma unroll
        for (int fm = 0; fm < 4; ++fm) {
            int m = wm + fm * 16 + lr;
            af[fm] = *(const bf16x8*)(As + m * 32 + ((q ^ (m & 3)) * 8));
        }
#pragma unroll
        for (int fn = 0; fn < NF; ++fn) {
            int n = wn + fn * 16 + lr;
            bfv[fn] = *(const bf16x8*)(Bs + n * 32 + ((q ^ (n & 3)) * 8));
        }
#pragma unroll
        for (int fm = 0; fm < 4; ++fm)
#pragma unroll
            for (int fn = 0; fn < NF; ++fn)
                acc[fm][fn] = __builtin_amdgcn_mfma_f32_16x16x32_bf16(
                    af[fm], bfv[fn], acc[fm][fn], 0, 0, 0);
    }

    // epilogue: C/D layout col=lane&15, row=(lane>>4)*4+reg
    const int rbase = q * 4;
#pragma unroll
    for (int fn = 0; fn < NF; ++fn) {
        const int col = n0 + wn + fn * 16 + lr;
        float bb = 0.f;
        if (bias1) bb += bias1[col];
        if (bias2) bb += bias2[col];
#pragma unroll
        for (int fm = 0; fm < 4; ++fm) {
            f32x4 v = acc[fm][fn];
#pragma unroll
            for (int r = 0; r < 4; ++r) {
                const int row = m0 + wm + fm * 16 + rbase + r;
                float val = v[r] + bb;
                if (ACT == 1) val = tanhf(val);
                C[(size_t)row * ldc + col] = val;
                if (Cb) Cb[(size_t)row * ldc + col] = (bf16)val;
            }
        }
    }
}

// ---------------- H1 GEMM with fused cat construction ----------------------
__global__ __launch_bounds__(256) void h1_gemm(
    const bf16* __restrict__ xb, const bf16* __restrict__ wbb,
    const bf16* __restrict__ W1b,
    const float* __restrict__ b1, float* __restrict__ H1)
{
    constexpr int BM = 128, BN = 64, BK = 32, NF = 2;
    constexpr int K = 512;
    __shared__ bf16 As[BM * BK];
    __shared__ bf16 Bs[BN * BK];
    const int tid  = threadIdx.x;
    const int wave = tid >> 6;
    const int lane = tid & 63;
    const int m0 = blockIdx.x * BM;
    const int wm = (wave >> 1) * 64;
    const int wn = (wave & 1) * 32;

    f32x4 acc[4][NF];
#pragma unroll
    for (int i = 0; i < 4; ++i)
#pragma unroll
        for (int j = 0; j < NF; ++j) acc[i][j] = (f32x4){0.f, 0.f, 0.f, 0.f};

    const int ar = tid >> 2;
    const int ac = tid & 3;
    const int sw = ac ^ (ar & 3);
    const int lr = lane & 15;
    const int q  = lane >> 4;

    for (int k0 = 0; k0 < K; k0 += BK) {
        __syncthreads();
#pragma unroll
        for (int it = 0; it < 2; ++it) {
            const int row = m0 + it * 64 + ar;
            const int b = row / (Ss - 1), t = row - b * (Ss - 1);
            const int col = k0 + sw * 8;
            const bf16* gp = (col < 256)
                ? xb  + (size_t)b * (Ss * Dd) + col
                : wbb + ((size_t)(b * Ss + t)) * Dd + (col - 256);
            GL2LDS(gp, As + it * 2048 + wave * 512);
        }
        {
            const bf16* gp = W1b + (size_t)ar * K + k0 + sw * 8;
            GL2LDS(gp, Bs + wave * 512);
        }
        __syncthreads();

        bf16x8 af[4], bfv[NF];
#pragma unroll
        for (int fm = 0; fm < 4; ++fm) {
            int m = wm + fm * 16 + lr;
            af[fm] = *(const bf16x8*)(As + m * 32 + ((q ^ (m & 3)) * 8));
        }
#pragma unroll
        for (int fn = 0; fn < NF; ++fn) {
            int n = wn + fn * 16 + lr;
            bfv[fn] = *(const bf16x8*)(Bs + n * 32 + ((q ^ (n & 3)) * 8));
        }
#pragma unroll
        for (int fm = 0; fm < 4; ++fm)
#pragma unroll
            for (int fn = 0; fn < NF; ++fn)
                acc[fm][fn] = __builtin_amdgcn_mfma_f32_16x16x32_bf16(
                    af[fm], bfv[fn], acc[fm][fn], 0, 0, 0);
    }

    const int rbase = q * 4;
#pragma unroll
    for (int fn = 0; fn < NF; ++fn) {
        const int col = wn + fn * 16 + lr;
        const float bb = b1[col];
#pragma unroll
        for (int fm = 0; fm < 4; ++fm) {
            f32x4 v = acc[fm][fn];
#pragma unroll
            for (int r = 0; r < 4; ++r) {
                const int row = m0 + wm + fm * 16 + rbase + r;
                H1[(size_t)row * 64 + col] = tanhf(v[r] + bb);
            }
        }
    }
}

// ---------------- fused LSTM recurrence (r7 config + per-wave flags) -------
// 64 blocks x 512 threads. Block (bm = blockIdx&15, bd = blockIdx>>4):
// batch rows bm*16..+15, hidden quarter [bd*64,+64). Wave w: kh = w>>2,
// ct = w&3; weights 4x4 frags = 64 VGPR (resident, VGPR=88).
// CHANGE vs r9: per-WAVE flags replace the single block flag + B2 barrier.
// Each receiver's 8B slot is written by exactly one remote WAVE (rowA>>2),
// so each sender wave does: stores -> own-wave s_waitcnt vmcnt(0) (no block
// barrier) -> store flag[slot][wave]; receivers poll the specific remote
// wave's flag. One fewer __syncthreads + no all-wave drain per step.
__global__ __launch_bounds__(512, 2) void lstm_quad(
    const bf16* __restrict__ Whhb,    // (1024 x 256) N x K
    const float* __restrict__ gates,  // (B*S x 1024) x@Wih^T+bih+bhh
    bf16* __restrict__ rnnb,          // (B*S x 256) h outputs + exchange
    unsigned* __restrict__ bar)       // flags: bar[(bm*4+bd)*32 + wave*8]
{
    __shared__ bf16 hb0[16 * 256];
    __shared__ bf16 hb1[16 * 256];
    __shared__ float pacc[4][4][16][17];
    const int tid  = threadIdx.x;
    const int w    = tid >> 6;
    const int lane = tid & 63;
    const int lr   = lane & 15;
    const int q    = lane >> 4;
    const int bm   = blockIdx.x & 15;
    const int bd   = blockIdx.x >> 4;       // 0..3
    const int kh   = w >> 2;                // K-half
    const int ct   = w & 3;                 // col tile
    const int dg   = bd * 64 + ct * 16 + lr;

    // ---- loop-invariant Whh fragments for this K-half: 64 VGPR ----
    f32x4 wfr[4][4];
#pragma unroll
    for (int g = 0; g < 4; ++g) {
        const bf16* brow = Whhb + (size_t)(g * 256 + dg) * Dd + kh * 128 + q * 8;
#pragma unroll
        for (int kc = 0; kc < 4; ++kc)
            wfr[g][kc] = *(const f32x4*)(brow + kc * 32);
    }

    // gate-preact pointers (kh=0 lanes): rows q*4+r, col dg
    const float* gp[4];
#pragma unroll
    for (int r = 0; r < 4; ++r)
        gp[r] = gates + (size_t)(bm * 16 + q * 4 + r) * (Ss * 1024) + dg;

    // pack/store role (tid < 256): 8 B = 4 cols of one row
    const int xrow = tid >> 4, xc8 = tid & 15;
    const size_t my_base = ((size_t)(bm * 16 + xrow) * Ss) * Dd + bd * 64 + xc8 * 4;
    const int pack_off = xrow * 512 + (((bd * 8 + (xc8 >> 1)) ^ (xrow & 7)) << 4) + (xc8 & 1) * 8;

    // remote-load slots: slot A (all 512 threads), slot B (tid < 256)
    const int pA  = tid >> 8;                         // 0 or 1
    const int pdA = pA + (pA >= bd ? 1 : 0);
    const int pdB = 2 + (2 >= bd ? 1 : 0);
    const int rowA = (tid >> 4) & 15, xqA = tid & 15;
    const size_t gA = ((size_t)(bm * 16 + rowA) * Ss) * Dd + pdA * 64 + xqA * 4;
    const size_t gB = ((size_t)(bm * 16 + xrow) * Ss) * Dd + pdB * 64 + xc8 * 4;
    const int unpA = rowA * 512 + (((pdA * 8 + (xqA >> 1)) ^ (rowA & 7)) << 4) + (xqA & 1) * 8;
    const int unpB = xrow * 512 + (((pdB * 8 + (xc8 >> 1)) ^ (xrow & 7)) << 4) + (xc8 & 1) * 8;
    unsigned* myfw = bar + (bm * 4 + bd) * 32;                       // + wave*8
    unsigned* pfAw = bar + (bm * 4 + pdA) * 32 + (rowA >> 2) * 8;    // remote wave's flag
    unsigned* pfBw = bar + (bm * 4 + pdB) * 32 + (xrow >> 2) * 8;

    // elementwise LDS write offsets (kh=0 lanes): row q*4+r, col dg
    int ew_off[4];
#pragma unroll
    for (int r = 0; r < 4; ++r) {
        const int row = q * 4 + r;
        ew_off[r] = row * 512 + (((dg >> 3) ^ (row & 7)) << 4) + (dg & 7) * 2;
    }

    float c[4] = {0.f, 0.f, 0.f, 0.f};
    float gaA[4][4], gaB[4][4];   // [gate][r], double-buffered preacts
    if (kh == 0) {
#pragma unroll
        for (int r = 0; r < 4; ++r)
#pragma unroll
            for (int g = 0; g < 4; ++g) gaA[g][r] = gp[r][g * 256];
    }

#define STEP(T, GACUR, GANEXT, RD, WR, FIRST)                                   \
    {                                                                           \
        f32x4 acc[4];                                                           \
        _Pragma("unroll")                                                       \
        for (int g = 0; g < 4; ++g) acc[g] = (f32x4){0.f, 0.f, 0.f, 0.f};       \
        if (!(FIRST)) {                                                         \
            bf16x8 af[4];                                                       \
            _Pragma("unroll")                                                   \
            for (int kc = 0; kc < 4; ++kc)                                      \
                af[kc] = *(const bf16x8*)((const char*)(RD) + lr * 512          \
                         + (((kh * 16 + kc * 4 + q) ^ (lr & 7)) << 4));         \
            _Pragma("unroll")                                                   \
            for (int kc = 0; kc < 4; ++kc)                                      \
                _Pragma("unroll")                                               \
                for (int g = 0; g < 4; ++g)                                     \
                    acc[g] = __builtin_amdgcn_mfma_f32_16x16x32_bf16(           \
                        af[kc], __builtin_bit_cast(bf16x8, wfr[g][kc]),         \
                        acc[g], 0, 0, 0);                                       \
        }                                                                       \
        if (kh == 1) {                                                          \
            _Pragma("unroll")                                                   \
            for (int g = 0; g < 4; ++g)                                         \
                _Pragma("unroll")                                               \
                for (int r = 0; r < 4; ++r)                                     \
                    pacc[ct][g][q * 4 + r][lr] = acc[g][r];                     \
        }                                                                       \
        __syncthreads();  /* Ba: kh1 partials visible */                        \
        if (kh == 0) {                                                          \
            _Pragma("unroll")                                                   \
            for (int r = 0; r < 4; ++r) {                                       \
                float gi = acc[0][r] + pacc[ct][0][q * 4 + r][lr] + GACUR[0][r];\
                float gf = acc[1][r] + pacc[ct][1][q * 4 + r][lr] + GACUR[1][r];\
                float gg = acc[2][r] + pacc[ct][2][q * 4 + r][lr] + GACUR[2][r];\
                float go = acc[3][r] + pacc[ct][3][q * 4 + r][lr] + GACUR[3][r];\
                float ii  = 1.f / (1.f + expf(-gi));                            \
                float ff  = 1.f / (1.f + expf(-gf));                            \
                float g2t = tanhf(gg);                                          \
                float oo  = 1.f / (1.f + expf(-go));                            \
                c[r] = ff * c[r] + ii * g2t;                                    \
                *(bf16*)((char*)(WR) + ew_off[r]) = (bf16)(oo * tanhf(c[r]));   \
            }                                                                   \
        }                                                                       \
        __syncthreads();  /* B1: local h slice in LDS */                        \
        if (tid < 256) {  /* send: store, own-wave drain, per-wave flag */      \
            u64 v = *(const u64*)((const char*)(WR) + pack_off);                \
            __hip_atomic_store((u64*)(rnnb + my_base + (size_t)(T) * Dd), v,    \
                               __ATOMIC_RELAXED, __HIP_MEMORY_SCOPE_AGENT);     \
            asm volatile("s_waitcnt vmcnt(0)" ::: "memory");                    \
            if ((tid & 63) == 0)                                                \
                __hip_atomic_store(myfw + (tid >> 6) * 8,                       \
                                   (unsigned)((T) + 1),                         \
                                   __ATOMIC_RELAXED, __HIP_MEMORY_SCOPE_AGENT); \
        }                                                                       \
        if ((T) != Ss - 1) {                                                    \
            if (kh == 0) {  /* preact prefetch hides under the poll */          \
                _Pragma("unroll")                                               \
                for (int r = 0; r < 4; ++r)                                     \
                    _Pragma("unroll")                                           \
                    for (int g = 0; g < 4; ++g)                                 \
                        GANEXT[g][r] = gp[r][(size_t)((T) + 1) * 1024 + g * 256];\
            }                                                                   \
            while (__hip_atomic_load(pfAw, __ATOMIC_RELAXED,                    \
                                     __HIP_MEMORY_SCOPE_AGENT)                  \
                   < (unsigned)((T) + 1)) {}                                    \
            {                                                                   \
                u64 rv = __hip_atomic_load(                                     \
                    (const u64*)(rnnb + gA + (size_t)(T) * Dd),                 \
                    __ATOMIC_RELAXED, __HIP_MEMORY_SCOPE_AGENT);                \
                *(u64*)((char*)(WR) + unpA) = rv;                               \
            }                                                                   \
            if (tid < 256) {                                                    \
                while (__hip_atomic_load(pfBw, __ATOMIC_RELAXED,                \
                                         __HIP_MEMORY_SCOPE_AGENT)              \
                       < (unsigned)((T) + 1)) {}                                \
                u64 rv = __hip_atomic_load(                                     \
                    (const u64*)(rnnb + gB + (size_t)(T) * Dd),                 \
                    __ATOMIC_RELAXED, __HIP_MEMORY_SCOPE_AGENT);                \
                *(u64*)((char*)(WR) + unpB) = rv;                               \
            }                                                                   \
            __syncthreads();  /* B4: full h_t (local+3 remote) in WR */         \
        }                                                                       \
    }

    for (int t2 = 0; t2 < Ss; t2 += 2) {
        STEP(t2,     gaA, gaB, hb1, hb0, (t2 == 0));
        STEP(t2 + 1, gaB, gaA, hb0, hb1, false);
    }
#undef STEP
}

// ---------------- fused prep: weight converts + Wdiff transpose + alpha ----
__global__ __launch_bounds__(256) void prep_kernel(
    const float* __restrict__ Wih, bf16* __restrict__ Wihb,
    const float* __restrict__ Whh, bf16* __restrict__ Whhb,
    const float* __restrict__ Whk, bf16* __restrict__ Whkb,
    const float* __restrict__ W1,  bf16* __restrict__ W1b,
    const float* __restrict__ Wdiff, bf16* __restrict__ WdTb,
    const int* __restrict__ tdiff, float* __restrict__ salpha,
    float* __restrict__ sbeta, unsigned* __restrict__ bar)
{
    __shared__ float t[32][33];
    int bx = blockIdx.x;
    const int tid = threadIdx.x;
    if (bx < 1024) { int i = bx * 256 + tid; Wihb[i] = (bf16)Wih[i]; return; }
    bx -= 1024;
    if (bx < 1024) { int i = bx * 256 + tid; Whhb[i] = (bf16)Whh[i]; return; }
    bx -= 1024;
    if (bx < 256)  { int i = bx * 256 + tid; Whkb[i] = (bf16)Whk[i]; return; }
    bx -= 256;
    if (bx < 128)  { int i = bx * 256 + tid; W1b[i]  = (bf16)W1[i];  return; }
    bx -= 128;
    if (bx < 64) {
        const int c0 = (bx & 7) * 32, r0 = (bx >> 3) * 32;
        const int tx = tid & 31, ty = tid >> 5;
        for (int i = ty; i < 32; i += 8)
            t[i][tx] = Wdiff[(size_t)(r0 + i) * 256 + c0 + tx];
        __syncthreads();
        for (int i = ty; i < 32; i += 8)
            WdTb[(size_t)(c0 + i) * 256 + r0 + tx] = (bf16)t[tx][i];
        return;
    }
    // alpha + per-wave barrier-flag init (64 slots x 32 words = 2048)
#pragma unroll
    for (int j = 0; j < 8; ++j) bar[tid * 8 + j] = 0u;
    const int tt = tdiff[tid];
    const float step = (0.02f - 1e-4f) / 999.f;
    float prod = 1.f;
    for (int j = 0; j <= tt; ++j) prod *= (1.f - (1e-4f + j * step));
    salpha[tid] = sqrtf(prod);
    sbeta[tid]  = sqrtf(fmaxf(1.f - prod, 0.f));
}

// ---------------- embedding gather-sum: wave-per-(b,s), float4 gathers -----
// r9's scalar version was latency-bound (64us, 46% HBM, 26% VALU): 40
// dependent-latency 4B gathers/thread. Now: wave w of each block owns row
// (blockIdx*4+w); lane l covers cols [l*4,l*4+4) via float4 -> 40
// INDEPENDENT 16B gathers per lane (4x bytes in flight per instr, 1/4 the
// instructions). Ascending-c accumulation order -> bit-identical to ref.
__global__ __launch_bounds__(256) void embed_kernel(
    const int* __restrict__ seqs, const float* __restrict__ emb,
    float* __restrict__ x, bf16* __restrict__ xb)
{
    __shared__ int idx[4][Cc];
    const int tid = threadIdx.x;
    const int w = tid >> 6, l = tid & 63;
    const int bs0 = blockIdx.x * 4;
    if (tid < 4 * Cc) idx[tid / Cc][tid % Cc] = seqs[(size_t)bs0 * Cc + tid];
    __syncthreads();
    f32x4 s = (f32x4){0.f, 0.f, 0.f, 0.f};
#pragma unroll 8
    for (int c = 0; c < Cc; ++c)
        s += *(const f32x4*)(emb + (size_t)idx[w][c] * Dd + l * 4);
    const size_t o = (size_t)(bs0 + w) * Dd + l * 4;
    *(f32x4*)(x + o) = s;
    bf16 b4[4] = {(bf16)s[0], (bf16)s[1], (bf16)s[2], (bf16)s[3]};
    *(u64*)(xb + o) = *(const u64*)b4;
}

// ---------------- fused attn logits + softmax + apply + diffusion + copy ---
__global__ __launch_bounds__(256) void attn_diff_kernel(
    const float* __restrict__ x, const float* __restrict__ w,
    const float* __restrict__ H1, const float* __restrict__ W2,
    const float* __restrict__ b2, const float* __restrict__ noise,
    const float* __restrict__ temb, const int* __restrict__ tdiff,
    const float* __restrict__ salpha, const float* __restrict__ sbeta,
    float* __restrict__ aligned, bf16* __restrict__ tmpb,
    float* __restrict__ noise_out)
{
    __shared__ float sa[2];
    const int bs = blockIdx.x;
    const int b = bs / Ss, s = bs % Ss;
    const int d = threadIdx.x;
    if (s > 0 && threadIdx.x < 64) {
        const int r = b * (Ss - 1) + (s - 1);
        const int j = threadIdx.x;
        float h = H1[(size_t)r * 64 + j];
        float v0 = h * W2[j];
        float v1 = h * W2[64 + j];
#pragma unroll
        for (int off = 32; off; off >>= 1) { v0 += __shfl_down(v0, off); v1 += __shfl_down(v1, off); }
        if (j == 0) {
            float z0 = v0 + b2[0], z1 = v1 + b2[1];
            float m = fmaxf(z0, z1);
            float e0 = expf(z0 - m), e1 = expf(z1 - m);
            float inv = 1.f / (e0 + e1);
            sa[0] = e0 * inv;
            sa[1] = e1 * inv;
        }
    }
    __syncthreads();
    const float ek = x[((size_t)b * Ss) * Dd + d];
    float v;
    if (s == 0) {
        v = ek;
    } else {
        v = ek * sa[0] + w[((size_t)b * Ss + s - 1) * Dd + d] * sa[1];
    }
    const size_t i = (size_t)bs * Dd + d;
    aligned[i] = v;
    const int t = tdiff[b];
    tmpb[i] = (bf16)(v * salpha[b] + noise[i] * sbeta[b] + temb[(size_t)t * Dd + d]);
    noise_out[i] = noise[i];   // passthrough output (replaces the D2D memcpy)
}

// ---------------- pooled 2-class heads ----------------
__device__ inline void pool_reduce_write(float m, const float* __restrict__ Wout,
                                         const float* __restrict__ bout,
                                         float* __restrict__ outp, int b,
                                         float* r0, float* r1)
{
    float v0 = m * Wout[threadIdx.x];
    float v1 = m * Wout[Dd + threadIdx.x];
#pragma unroll
    for (int off = 32; off; off >>= 1) { v0 += __shfl_down(v0, off); v1 += __shfl_down(v1, off); }
    const int lane = threadIdx.x & 63, wv = threadIdx.x >> 6;
    if (lane == 0) { r0[wv] = v0; r1[wv] = v1; }
    __syncthreads();
    if (threadIdx.x == 0) {
        outp[b * 2 + 0] = r0[0] + r0[1] + r0[2] + r0[3] + bout[0];
        outp[b * 2 + 1] = r1[0] + r1[1] + r1[2] + r1[3] + bout[1];
    }
}

__global__ __launch_bounds__(256) void pool_x_kernel(
    const float* __restrict__ x, const float* __restrict__ Wout,
    const float* __restrict__ bout, float* __restrict__ outp)
{
    __shared__ float r0[4], r1[4];
    const int b = blockIdx.x, d = threadIdx.x;
    float m = -INFINITY;
    for (int s = 0; s < Ss; ++s) m = fmaxf(m, x[((size_t)b * Ss + s) * Dd + d]);
    pool_reduce_write(m, Wout, bout, outp, b, r0, r1);
}

__global__ __launch_bounds__(256) void gen_pool_kernel(
    const float* __restrict__ aligned, const float* __restrict__ noise,
    const float* __restrict__ pred, const float* __restrict__ Wout,
    const float* __restrict__ bout, float* __restrict__ outp)
{
    __shared__ float r0[4], r1[4];
    const int b = blockIdx.x, d = threadIdx.x;
    float m = -INFINITY;
    for (int s = 0; s < Ss; ++s) {
        const size_t i = ((size_t)b * Ss + s) * Dd + d;
        m = fmaxf(m, aligned[i] + noise[i] - pred[i]);
    }
    pool_reduce_write(m, Wout, bout, outp, b, r0, r1);
}

// ---------------- host ----------------
extern "C" void kernel_launch(void* const* d_in, const int* in_sizes, int n_in,
                              void* d_out, int out_size, void* d_ws, size_t ws_size,
                              hipStream_t stream)
{
    const int*   seqs  = (const int*)d_in[0];
    const int*   tdiff = (const int*)d_in[5];
    const float* noise = (const float*)d_in[6];
    const float* emb   = (const float*)d_in[7];
    const float* Wih   = (const float*)d_in[8];
    const float* Whh   = (const float*)d_in[9];
    const float* bih   = (const float*)d_in[10];
    const float* bhh   = (const float*)d_in[11];
    const float* Whk   = (const float*)d_in[12];
    const float* bhk   = (const float*)d_in[13];
    const float* W1    = (const float*)d_in[14];
    const float* b1    = (const float*)d_in[15];
    const float* W2    = (const float*)d_in[16];
    const float* b2    = (const float*)d_in[17];
    const float* Wdiff = (const float*)d_in[18];
    const float* bdiff = (const float*)d_in[19];
    const float* temb  = (const float*)d_in[20];
    const float* Wout  = (const float*)d_in[21];
    const float* bout  = (const float*)d_in[22];

    float* outp = (float*)d_out;
    char*  wsb  = (char*)d_ws;

    float* gates   = (float*)(wsb + OFFB_GATES);
    float* aligned = (float*)(wsb + OFFB_ALIGNED);
    bf16*  wbb     = (bf16*) (wsb + OFFB_WBB);
    bf16*  tmpb    = (bf16*) (wsb + OFFB_TMPB);
    float* H1      = (float*)(wsb + OFFB_H1);
    float* x       = (float*)(wsb + OFFB_X);
    bf16*  xb      = (bf16*) (wsb + OFFB_XB);
    bf16*  rnnb    = (bf16*) (wsb + OFFB_RNNB);
    float* wbuf    = (float*)(wsb + OFFB_W);
    unsigned* bar  = (unsigned*)(wsb + OFFB_BAR);
    bf16*  Wihb    = (bf16*) (wsb + OFFB_WIHB);
    bf16*  Whhb    = (bf16*) (wsb + OFFB_WHHB);
    bf16*  Whkb    = (bf16*) (wsb + OFFB_WHKB);
    bf16*  W1b     = (bf16*) (wsb + OFFB_W1B);
    bf16*  WdTb    = (bf16*) (wsb + OFFB_WDTB);
    float* salpha  = (float*)(wsb + OFFB_SALPHA);
    float* sbeta   = (float*)(wsb + OFFB_SBETA);

    float* pred_out  = outp + 1024;                        // (B,S,D)
    float* noise_out = outp + 1024 + (size_t)Bb * Ss * Dd; // (B,S,D)

    // fused prep: all weight converts + Wdiff transpose + alpha + flag init
    prep_kernel<<<2497, 256, 0, stream>>>(Wih, Wihb, Whh, Whhb, Whk, Whkb,
                                          W1, W1b, Wdiff, WdTb,
                                          tdiff, salpha, sbeta, bar);

    // x = emb[seqs].sum(axis=2)  (fp32 + bf16), wave-per-(b,s) float4
    embed_kernel<<<(Bb * Ss) / 4, 256, 0, stream>>>(seqs, emb, x, xb);

    // pool_x head (only needs x)
    pool_x_kernel<<<Bb, 256, 0, stream>>>(x, Wout, bout, outp);

    // gates_pre = x @ Wih^T + bih + bhh : (12800 x 1024), K=256
    mfma_gemm<128, 128, 0><<<dim3(100, 8), 256, 0, stream>>>(
        xb, 256, Wihb, 256, bih, bhh, gates, nullptr, 1024, 256);

    // LSTM recurrence: ONE launch, 64 blocks, per-wave-flag exchange
    lstm_quad<<<64, 512, 0, stream>>>(Whhb, gates, rnnb, bar);

    // w = rnn @ Whk^T + bhk : fp32 wbuf + bf16 wbb (feeds fused-cat H1 GEMM)
    mfma_gemm<128, 128, 0><<<dim3(100, 2), 256, 0, stream>>>(
        rnnb, 256, Whkb, 256, bhk, nullptr, wbuf, wbb, 256, 256);

    // H1 = tanh(cat @ W1^T + b1), cat built on the fly from xb/wbb
    h1_gemm<<<dim3(98, 1), 256, 0, stream>>>(xb, wbb, W1b, b1, H1);

    // fused: attn logits+softmax, apply, diffusion elementwise, noise copy
    attn_diff_kernel<<<Bb * Ss, 256, 0, stream>>>(
        x, wbuf, H1, W2, b2, noise, temb, tdiff, salpha, sbeta,
        aligned, tmpb, noise_out);

    // predicted_noise = tmp @ Wdiff + bdiff -> d_out
    mfma_gemm<128, 128, 0><<<dim3(100, 2), 256, 0, stream>>>(
        tmpb, 256, WdTb, 256, bdiff, nullptr, pred_out, nullptr, 256, 256);

    // gen_pool head: max_s(aligned + noise - pred) @ Wout^T + bout
    gen_pool_kernel<<<Bb, 256, 0, stream>>>(aligned, noise, pred_out, Wout, bout, outp + 512);
}

// Round 11
// 470.840 us; speedup vs baseline: 1.0852x; 1.0852x over previous
//
#include <hip/hip_runtime.h>
#include <cmath>

// Problem constants
#define Bb 256
#define Ss 50
#define Cc 40
#define Dd 256
#define Vv 20000

typedef __bf16 bf16;
typedef __bf16 bf16x8 __attribute__((ext_vector_type(8)));
typedef float f32x4 __attribute__((ext_vector_type(4)));
typedef unsigned long long u64;

#define GL2LDS(g, l) __builtin_amdgcn_global_load_lds( \
    (__attribute__((address_space(1))) void*)(g), \
    (__attribute__((address_space(3))) void*)(l), 16, 0, 0)

// ---------------- ws layout (BYTE offsets) ----------------
#define OFFB_GATES    0ull
#define OFFB_ALIGNED  0ull
#define OFFB_WBB      13107200ull
#define OFFB_TMPB     25952256ull
#define OFFB_H1       32505856ull
#define OFFB_X        52428800ull
#define OFFB_XB       65536000ull
#define OFFB_RNNB     72089600ull
#define OFFB_W        78643200ull
#define OFFB_BAR      91750400ull
#define OFFB_WIHB     92012544ull
#define OFFB_WHHB     92536832ull
#define OFFB_WHKB     93061120ull
#define OFFB_W1B      93192192ull
#define OFFB_WDTB     93257728ull
#define OFFB_SALPHA   93388800ull
#define OFFB_SBETA    93389824ull

// ---------------- bf16 MFMA GEMM (optional extra bf16 output Cb) ----------
template<int BM, int BN, int ACT>
__global__ __launch_bounds__(256) void mfma_gemm(
    const bf16* __restrict__ A, int lda,
    const bf16* __restrict__ B, int ldb,
    const float* __restrict__ bias1, const float* __restrict__ bias2,
    float* __restrict__ C, bf16* __restrict__ Cb, int ldc, int K)
{
    constexpr int BK = 32;
    constexpr int NF = BN / 32;           // n-frags per wave (2x2 wave grid)
    __shared__ bf16 As[BM * BK];
    __shared__ bf16 Bs[BN * BK];
    const int tid  = threadIdx.x;
    const int wave = tid >> 6;
    const int lane = tid & 63;
    const int m0 = blockIdx.x * BM;
    const int n0 = blockIdx.y * BN;
    const int wm = (wave >> 1) * 64;      // wave row offset in tile
    const int wn = (wave & 1) * (BN / 2); // wave col offset in tile

    f32x4 acc[4][NF];
#pragma unroll
    for (int i = 0; i < 4; ++i)
#pragma unroll
        for (int j = 0; j < NF; ++j) acc[i][j] = (f32x4){0.f, 0.f, 0.f, 0.f};

    const int ar = tid >> 2;              // staging row (0..63) within iter
    const int ac = tid & 3;               // staging chunk
    const int sw = ac ^ (ar & 3);         // swizzled source chunk
    const int lr = lane & 15;
    const int q  = lane >> 4;             // k-chunk of fragment

    for (int k0 = 0; k0 < K; k0 += BK) {
        __syncthreads();
#pragma unroll
        for (int it = 0; it < BM / 64; ++it) {
            const bf16* gp = A + (size_t)(m0 + it * 64 + ar) * lda + k0 + sw * 8;
            GL2LDS(gp, As + it * 2048 + wave * 512);
        }
#pragma unroll
        for (int it = 0; it < BN / 64; ++it) {
            const bf16* gp = B + (size_t)(n0 + it * 64 + ar) * ldb + k0 + sw * 8;
            GL2LDS(gp, Bs + it * 2048 + wave * 512);
        }
        __syncthreads();

        bf16x8 af[4], bfv[NF];
#pragma unroll
        for (int fm = 0; fm < 4; ++fm) {
            int m = wm + fm * 16 + lr;
            af[fm] = *(const bf16x8*)(As + m * 32 + ((q ^ (m & 3)) * 8));
        }
#pragma unroll
        for (int fn = 0; fn < NF; ++fn) {
            int n = wn + fn * 16 + lr;
            bfv[fn] = *(const bf16x8*)(Bs + n * 32 + ((q ^ (n & 3)) * 8));
        }
#pragma unroll
        for (int fm = 0; fm < 4; ++fm)
#pragma unroll
            for (int fn = 0; fn < NF; ++fn)
                acc[fm][fn] = __builtin_amdgcn_mfma_f32_16x16x32_bf16(
                    af[fm], bfv[fn], acc[fm][fn], 0, 0, 0);
    }

    // epilogue: C/D layout col=lane&15, row=(lane>>4)*4+reg
    const int rbase = q * 4;
#pragma unroll
    for (int fn = 0; fn < NF; ++fn) {
        const int col = n0 + wn + fn * 16 + lr;
        float bb = 0.f;
        if (bias1) bb += bias1[col];
        if (bias2) bb += bias2[col];
#pragma unroll
        for (int fm = 0; fm < 4; ++fm) {
            f32x4 v = acc[fm][fn];
#pragma unroll
            for (int r = 0; r < 4; ++r) {
                const int row = m0 + wm + fm * 16 + rbase + r;
                float val = v[r] + bb;
                if (ACT == 1) val = tanhf(val);
                C[(size_t)row * ldc + col] = val;
                if (Cb) Cb[(size_t)row * ldc + col] = (bf16)val;
            }
        }
    }
}

// ---------------- H1 GEMM with fused cat construction ----------------------
__global__ __launch_bounds__(256) void h1_gemm(
    const bf16* __restrict__ xb, const bf16* __restrict__ wbb,
    const bf16* __restrict__ W1b,
    const float* __restrict__ b1, float* __restrict__ H1)
{
    constexpr int BM = 128, BN = 64, BK = 32, NF = 2;
    constexpr int K = 512;
    __shared__ bf16 As[BM * BK];
    __shared__ bf16 Bs[BN * BK];
    const int tid  = threadIdx.x;
    const int wave = tid >> 6;
    const int lane = tid & 63;
    const int m0 = blockIdx.x * BM;
    const int wm = (wave >> 1) * 64;
    const int wn = (wave & 1) * 32;

    f32x4 acc[4][NF];
#pragma unroll
    for (int i = 0; i < 4; ++i)
#pragma unroll
        for (int j = 0; j < NF; ++j) acc[i][j] = (f32x4){0.f, 0.f, 0.f, 0.f};

    const int ar = tid >> 2;
    const int ac = tid & 3;
    const int sw = ac ^ (ar & 3);
    const int lr = lane & 15;
    const int q  = lane >> 4;

    for (int k0 = 0; k0 < K; k0 += BK) {
        __syncthreads();
#pragma unroll
        for (int it = 0; it < 2; ++it) {
            const int row = m0 + it * 64 + ar;
            const int b = row / (Ss - 1), t = row - b * (Ss - 1);
            const int col = k0 + sw * 8;
            const bf16* gp = (col < 256)
                ? xb  + (size_t)b * (Ss * Dd) + col
                : wbb + ((size_t)(b * Ss + t)) * Dd + (col - 256);
            GL2LDS(gp, As + it * 2048 + wave * 512);
        }
        {
            const bf16* gp = W1b + (size_t)ar * K + k0 + sw * 8;
            GL2LDS(gp, Bs + wave * 512);
        }
        __syncthreads();

        bf16x8 af[4], bfv[NF];
#pragma unroll
        for (int fm = 0; fm < 4; ++fm) {
            int m = wm + fm * 16 + lr;
            af[fm] = *(const bf16x8*)(As + m * 32 + ((q ^ (m & 3)) * 8));
        }
#pragma unroll
        for (int fn = 0; fn < NF; ++fn) {
            int n = wn + fn * 16 + lr;
            bfv[fn] = *(const bf16x8*)(Bs + n * 32 + ((q ^ (n & 3)) * 8));
        }
#pragma unroll
        for (int fm = 0; fm < 4; ++fm)
#pragma unroll
            for (int fn = 0; fn < NF; ++fn)
                acc[fm][fn] = __builtin_amdgcn_mfma_f32_16x16x32_bf16(
                    af[fm], bfv[fn], acc[fm][fn], 0, 0, 0);
    }

    const int rbase = q * 4;
#pragma unroll
    for (int fn = 0; fn < NF; ++fn) {
        const int col = wn + fn * 16 + lr;
        const float bb = b1[col];
#pragma unroll
        for (int fm = 0; fm < 4; ++fm) {
            f32x4 v = acc[fm][fn];
#pragma unroll
            for (int r = 0; r < 4; ++r) {
                const int row = m0 + wm + fm * 16 + rbase + r;
                H1[(size_t)row * 64 + col] = tanhf(v[r] + bb);
            }
        }
    }
}

// ---------------- fused LSTM recurrence (r9 exchange) + pool_x overlay -----
// Blocks 0..63: recurrence (r9's measured-best protocol: block flag + B2
// barrier — r10's per-wave flags regressed 167->202us, reverted). Blocks
// 64..319: pool_x head, one block per batch b, running on the ~192 CUs the
// recurrence leaves idle (all 320 blocks co-resident: 33KB LDS, 88 VGPR ->
// >=2 blocks/CU capacity, so no dispatch-order deadlock risk).
__global__ __launch_bounds__(512, 2) void lstm_quad(
    const bf16* __restrict__ Whhb,    // (1024 x 256) N x K
    const float* __restrict__ gates,  // (B*S x 1024) x@Wih^T+bih+bhh
    bf16* __restrict__ rnnb,          // (B*S x 256) h outputs + exchange
    unsigned* __restrict__ bar,       // flags: bar[(bm*4+bd)*32]
    const float* __restrict__ xf,     // (B*S x 256) fp32 x (pool input)
    const float* __restrict__ Wout, const float* __restrict__ bout,
    float* __restrict__ outp)
{
    if (blockIdx.x >= 64) {
        // ---- pool_x overlay: max_s x[b,s,:] @ Wout^T + bout ----
        __shared__ float r0[4], r1[4];
        const int b = blockIdx.x - 64;
        const int tid = threadIdx.x;
        if (tid < 256) {
            float m = -INFINITY;
            for (int s = 0; s < Ss; ++s)
                m = fmaxf(m, xf[((size_t)b * Ss + s) * Dd + tid]);
            float v0 = m * Wout[tid];
            float v1 = m * Wout[Dd + tid];
#pragma unroll
            for (int off = 32; off; off >>= 1) {
                v0 += __shfl_down(v0, off);
                v1 += __shfl_down(v1, off);
            }
            if ((tid & 63) == 0) { r0[tid >> 6] = v0; r1[tid >> 6] = v1; }
        }
        __syncthreads();
        if (tid == 0) {
            outp[b * 2 + 0] = r0[0] + r0[1] + r0[2] + r0[3] + bout[0];
            outp[b * 2 + 1] = r1[0] + r1[1] + r1[2] + r1[3] + bout[1];
        }
        return;
    }

    __shared__ bf16 hb0[16 * 256];
    __shared__ bf16 hb1[16 * 256];
    __shared__ float pacc[4][4][16][17];
    const int tid  = threadIdx.x;
    const int w    = tid >> 6;
    const int lane = tid & 63;
    const int lr   = lane & 15;
    const int q    = lane >> 4;
    const int bm   = blockIdx.x & 15;
    const int bd   = blockIdx.x >> 4;       // 0..3
    const int kh   = w >> 2;                // K-half
    const int ct   = w & 3;                 // col tile
    const int dg   = bd * 64 + ct * 16 + lr;

    // ---- loop-invariant Whh fragments for this K-half: 64 VGPR ----
    f32x4 wfr[4][4];
#pragma unroll
    for (int g = 0; g < 4; ++g) {
        const bf16* brow = Whhb + (size_t)(g * 256 + dg) * Dd + kh * 128 + q * 8;
#pragma unroll
        for (int kc = 0; kc < 4; ++kc)
            wfr[g][kc] = *(const f32x4*)(brow + kc * 32);
    }

    // gate-preact pointers (kh=0 lanes): rows q*4+r, col dg
    const float* gp[4];
#pragma unroll
    for (int r = 0; r < 4; ++r)
        gp[r] = gates + (size_t)(bm * 16 + q * 4 + r) * (Ss * 1024) + dg;

    // pack/store role (tid < 256): 8 B = 4 cols of one row
    const int xrow = tid >> 4, xc8 = tid & 15;
    const size_t my_base = ((size_t)(bm * 16 + xrow) * Ss) * Dd + bd * 64 + xc8 * 4;
    const int pack_off = xrow * 512 + (((bd * 8 + (xc8 >> 1)) ^ (xrow & 7)) << 4) + (xc8 & 1) * 8;

    // remote-load slots: slot A (all 512 threads), slot B (tid < 256)
    const int pA  = tid >> 8;                         // 0 or 1
    const int pdA = pA + (pA >= bd ? 1 : 0);
    const int pdB = 2 + (2 >= bd ? 1 : 0);
    const int rowA = (tid >> 4) & 15, xqA = tid & 15;
    const size_t gA = ((size_t)(bm * 16 + rowA) * Ss) * Dd + pdA * 64 + xqA * 4;
    const size_t gB = ((size_t)(bm * 16 + xrow) * Ss) * Dd + pdB * 64 + xc8 * 4;
    const int unpA = rowA * 512 + (((pdA * 8 + (xqA >> 1)) ^ (rowA & 7)) << 4) + (xqA & 1) * 8;
    const int unpB = xrow * 512 + (((pdB * 8 + (xc8 >> 1)) ^ (xrow & 7)) << 4) + (xc8 & 1) * 8;
    unsigned* myf = bar + (bm * 4 + bd) * 32;
    unsigned* pfA = bar + (bm * 4 + pdA) * 32;
    unsigned* pfB = bar + (bm * 4 + pdB) * 32;

    // elementwise LDS write offsets (kh=0 lanes): row q*4+r, col dg
    int ew_off[4];
#pragma unroll
    for (int r = 0; r < 4; ++r) {
        const int row = q * 4 + r;
        ew_off[r] = row * 512 + (((dg >> 3) ^ (row & 7)) << 4) + (dg & 7) * 2;
    }

    float c[4] = {0.f, 0.f, 0.f, 0.f};
    float gaA[4][4], gaB[4][4];   // [gate][r], double-buffered preacts
    if (kh == 0) {
#pragma unroll
        for (int r = 0; r < 4; ++r)
#pragma unroll
            for (int g = 0; g < 4; ++g) gaA[g][r] = gp[r][g * 256];
    }

#define STEP(T, GACUR, GANEXT, RD, WR, FIRST)                                   \
    {                                                                           \
        f32x4 acc[4];                                                           \
        _Pragma("unroll")                                                       \
        for (int g = 0; g < 4; ++g) acc[g] = (f32x4){0.f, 0.f, 0.f, 0.f};       \
        if (!(FIRST)) {                                                         \
            bf16x8 af[4];                                                       \
            _Pragma("unroll")                                                   \
            for (int kc = 0; kc < 4; ++kc)                                      \
                af[kc] = *(const bf16x8*)((const char*)(RD) + lr * 512          \
                         + (((kh * 16 + kc * 4 + q) ^ (lr & 7)) << 4));         \
            _Pragma("unroll")                                                   \
            for (int kc = 0; kc < 4; ++kc)                                      \
                _Pragma("unroll")                                               \
                for (int g = 0; g < 4; ++g)                                     \
                    acc[g] = __builtin_amdgcn_mfma_f32_16x16x32_bf16(           \
                        af[kc], __builtin_bit_cast(bf16x8, wfr[g][kc]),         \
                        acc[g], 0, 0, 0);                                       \
        }                                                                       \
        if (kh == 1) {                                                          \
            _Pragma("unroll")                                                   \
            for (int g = 0; g < 4; ++g)                                         \
                _Pragma("unroll")                                               \
                for (int r = 0; r < 4; ++r)                                     \
                    pacc[ct][g][q * 4 + r][lr] = acc[g][r];                     \
        }                                                                       \
        __syncthreads();  /* Ba: kh1 partials visible */                        \
        if (kh == 0) {                                                          \
            _Pragma("unroll")                                                   \
            for (int r = 0; r < 4; ++r) {                                       \
                float gi = acc[0][r] + pacc[ct][0][q * 4 + r][lr] + GACUR[0][r];\
                float gf = acc[1][r] + pacc[ct][1][q * 4 + r][lr] + GACUR[1][r];\
                float gg = acc[2][r] + pacc[ct][2][q * 4 + r][lr] + GACUR[2][r];\
                float go = acc[3][r] + pacc[ct][3][q * 4 + r][lr] + GACUR[3][r];\
                float ii  = 1.f / (1.f + expf(-gi));                            \
                float ff  = 1.f / (1.f + expf(-gf));                            \
                float g2t = tanhf(gg);                                          \
                float oo  = 1.f / (1.f + expf(-go));                            \
                c[r] = ff * c[r] + ii * g2t;                                    \
                *(bf16*)((char*)(WR) + ew_off[r]) = (bf16)(oo * tanhf(c[r]));   \
            }                                                                   \
        }                                                                       \
        __syncthreads();  /* B1: local h slice in LDS */                        \
        if (tid < 256) {                                                        \
            u64 v = *(const u64*)((const char*)(WR) + pack_off);                \
            __hip_atomic_store((u64*)(rnnb + my_base + (size_t)(T) * Dd), v,    \
                               __ATOMIC_RELAXED, __HIP_MEMORY_SCOPE_AGENT);     \
        }                                                                       \
        if ((T) != Ss - 1) {                                                    \
            __syncthreads();  /* B2: per-wave vmcnt(0) -> stores at LLC */      \
            if (tid == 0)                                                       \
                __hip_atomic_store(myf, (unsigned)((T) + 1),                    \
                                   __ATOMIC_RELAXED, __HIP_MEMORY_SCOPE_AGENT); \
            if (kh == 0) {  /* preact prefetch hides under exchange */          \
                _Pragma("unroll")                                               \
                for (int r = 0; r < 4; ++r)                                     \
                    _Pragma("unroll")                                           \
                    for (int g = 0; g < 4; ++g)                                 \
                        GANEXT[g][r] = gp[r][(size_t)((T) + 1) * 1024 + g * 256];\
            }                                                                   \
            while (__hip_atomic_load(pfA, __ATOMIC_RELAXED,                     \
                                     __HIP_MEMORY_SCOPE_AGENT)                  \
                   < (unsigned)((T) + 1)) {}                                    \
            {                                                                   \
                u64 rv = __hip_atomic_load(                                     \
                    (const u64*)(rnnb + gA + (size_t)(T) * Dd),                 \
                    __ATOMIC_RELAXED, __HIP_MEMORY_SCOPE_AGENT);                \
                *(u64*)((char*)(WR) + unpA) = rv;                               \
            }                                                                   \
            if (tid < 256) {                                                    \
                while (__hip_atomic_load(pfB, __ATOMIC_RELAXED,                 \
                                         __HIP_MEMORY_SCOPE_AGENT)              \
                       < (unsigned)((T) + 1)) {}                                \
                u64 rv = __hip_atomic_load(                                     \
                    (const u64*)(rnnb + gB + (size_t)(T) * Dd),                 \
                    __ATOMIC_RELAXED, __HIP_MEMORY_SCOPE_AGENT);                \
                *(u64*)((char*)(WR) + unpB) = rv;                               \
            }                                                                   \
            __syncthreads();  /* B4: full h_t (local+3 remote) in WR */         \
        }                                                                       \
    }

    for (int t2 = 0; t2 < Ss; t2 += 2) {
        STEP(t2,     gaA, gaB, hb1, hb0, (t2 == 0));
        STEP(t2 + 1, gaB, gaA, hb0, hb1, false);
    }
#undef STEP
}

// ---------------- fused prep: weight converts + Wdiff transpose + alpha ----
__global__ __launch_bounds__(256) void prep_kernel(
    const float* __restrict__ Wih, bf16* __restrict__ Wihb,
    const float* __restrict__ Whh, bf16* __restrict__ Whhb,
    const float* __restrict__ Whk, bf16* __restrict__ Whkb,
    const float* __restrict__ W1,  bf16* __restrict__ W1b,
    const float* __restrict__ Wdiff, bf16* __restrict__ WdTb,
    const int* __restrict__ tdiff, float* __restrict__ salpha,
    float* __restrict__ sbeta, unsigned* __restrict__ bar)
{
    __shared__ float t[32][33];
    int bx = blockIdx.x;
    const int tid = threadIdx.x;
    if (bx < 1024) { int i = bx * 256 + tid; Wihb[i] = (bf16)Wih[i]; return; }
    bx -= 1024;
    if (bx < 1024) { int i = bx * 256 + tid; Whhb[i] = (bf16)Whh[i]; return; }
    bx -= 1024;
    if (bx < 256)  { int i = bx * 256 + tid; Whkb[i] = (bf16)Whk[i]; return; }
    bx -= 256;
    if (bx < 128)  { int i = bx * 256 + tid; W1b[i]  = (bf16)W1[i];  return; }
    bx -= 128;
    if (bx < 64) {
        const int c0 = (bx & 7) * 32, r0 = (bx >> 3) * 32;
        const int tx = tid & 31, ty = tid >> 5;
        for (int i = ty; i < 32; i += 8)
            t[i][tx] = Wdiff[(size_t)(r0 + i) * 256 + c0 + tx];
        __syncthreads();
        for (int i = ty; i < 32; i += 8)
            WdTb[(size_t)(c0 + i) * 256 + r0 + tx] = (bf16)t[tx][i];
        return;
    }
    // alpha + barrier-flag init (64 flag slots x 32 words = 2048)
#pragma unroll
    for (int j = 0; j < 8; ++j) bar[tid * 8 + j] = 0u;
    const int tt = tdiff[tid];
    const float step = (0.02f - 1e-4f) / 999.f;
    float prod = 1.f;
    for (int j = 0; j <= tt; ++j) prod *= (1.f - (1e-4f + j * step));
    salpha[tid] = sqrtf(prod);
    sbeta[tid]  = sqrtf(fmaxf(1.f - prod, 0.f));
}

// ---------------- embedding gather-sum: wave-per-(b,s), float4 gathers -----
__global__ __launch_bounds__(256) void embed_kernel(
    const int* __restrict__ seqs, const float* __restrict__ emb,
    float* __restrict__ x, bf16* __restrict__ xb)
{
    __shared__ int idx[4][Cc];
    const int tid = threadIdx.x;
    const int w = tid >> 6, l = tid & 63;
    const int bs0 = blockIdx.x * 4;
    if (tid < 4 * Cc) idx[tid / Cc][tid % Cc] = seqs[(size_t)bs0 * Cc + tid];
    __syncthreads();
    f32x4 s = (f32x4){0.f, 0.f, 0.f, 0.f};
#pragma unroll 8
    for (int c = 0; c < Cc; ++c)
        s += *(const f32x4*)(emb + (size_t)idx[w][c] * Dd + l * 4);
    const size_t o = (size_t)(bs0 + w) * Dd + l * 4;
    *(f32x4*)(x + o) = s;
    bf16 b4[4] = {(bf16)s[0], (bf16)s[1], (bf16)s[2], (bf16)s[3]};
    *(u64*)(xb + o) = *(const u64*)b4;
}

// ---------------- fused attn logits + softmax + apply + diffusion + copy ---
__global__ __launch_bounds__(256) void attn_diff_kernel(
    const float* __restrict__ x, const float* __restrict__ w,
    const float* __restrict__ H1, const float* __restrict__ W2,
    const float* __restrict__ b2, const float* __restrict__ noise,
    const float* __restrict__ temb, const int* __restrict__ tdiff,
    const float* __restrict__ salpha, const float* __restrict__ sbeta,
    float* __restrict__ aligned, bf16* __restrict__ tmpb,
    float* __restrict__ noise_out)
{
    __shared__ float sa[2];
    const int bs = blockIdx.x;
    const int b = bs / Ss, s = bs % Ss;
    const int d = threadIdx.x;
    if (s > 0 && threadIdx.x < 64) {
        const int r = b * (Ss - 1) + (s - 1);
        const int j = threadIdx.x;
        float h = H1[(size_t)r * 64 + j];
        float v0 = h * W2[j];
        float v1 = h * W2[64 + j];
#pragma unroll
        for (int off = 32; off; off >>= 1) { v0 += __shfl_down(v0, off); v1 += __shfl_down(v1, off); }
        if (j == 0) {
            float z0 = v0 + b2[0], z1 = v1 + b2[1];
            float m = fmaxf(z0, z1);
            float e0 = expf(z0 - m), e1 = expf(z1 - m);
            float inv = 1.f / (e0 + e1);
            sa[0] = e0 * inv;
            sa[1] = e1 * inv;
        }
    }
    __syncthreads();
    const float ek = x[((size_t)b * Ss) * Dd + d];
    float v;
    if (s == 0) {
        v = ek;
    } else {
        v = ek * sa[0] + w[((size_t)b * Ss + s - 1) * Dd + d] * sa[1];
    }
    const size_t i = (size_t)bs * Dd + d;
    aligned[i] = v;
    const int t = tdiff[b];
    tmpb[i] = (bf16)(v * salpha[b] + noise[i] * sbeta[b] + temb[(size_t)t * Dd + d]);
    noise_out[i] = noise[i];   // passthrough output (replaces the D2D memcpy)
}

// ---------------- gen_pool head ----------------
__global__ __launch_bounds__(256) void gen_pool_kernel(
    const float* __restrict__ aligned, const float* __restrict__ noise,
    const float* __restrict__ pred, const float* __restrict__ Wout,
    const float* __restrict__ bout, float* __restrict__ outp)
{
    __shared__ float r0[4], r1[4];
    const int b = blockIdx.x, d = threadIdx.x;
    float m = -INFINITY;
    for (int s = 0; s < Ss; ++s) {
        const size_t i = ((size_t)b * Ss + s) * Dd + d;
        m = fmaxf(m, aligned[i] + noise[i] - pred[i]);
    }
    float v0 = m * Wout[d];
    float v1 = m * Wout[Dd + d];
#pragma unroll
    for (int off = 32; off; off >>= 1) { v0 += __shfl_down(v0, off); v1 += __shfl_down(v1, off); }
    const int lane = d & 63, wv = d >> 6;
    if (lane == 0) { r0[wv] = v0; r1[wv] = v1; }
    __syncthreads();
    if (d == 0) {
        outp[b * 2 + 0] = r0[0] + r0[1] + r0[2] + r0[3] + bout[0];
        outp[b * 2 + 1] = r1[0] + r1[1] + r1[2] + r1[3] + bout[1];
    }
}

// ---------------- host ----------------
extern "C" void kernel_launch(void* const* d_in, const int* in_sizes, int n_in,
                              void* d_out, int out_size, void* d_ws, size_t ws_size,
                              hipStream_t stream)
{
    const int*   seqs  = (const int*)d_in[0];
    const int*   tdiff = (const int*)d_in[5];
    const float* noise = (const float*)d_in[6];
    const float* emb   = (const float*)d_in[7];
    const float* Wih   = (const float*)d_in[8];
    const float* Whh   = (const float*)d_in[9];
    const float* bih   = (const float*)d_in[10];
    const float* bhh   = (const float*)d_in[11];
    const float* Whk   = (const float*)d_in[12];
    const float* bhk   = (const float*)d_in[13];
    const float* W1    = (const float*)d_in[14];
    const float* b1    = (const float*)d_in[15];
    const float* W2    = (const float*)d_in[16];
    const float* b2    = (const float*)d_in[17];
    const float* Wdiff = (const float*)d_in[18];
    const float* bdiff = (const float*)d_in[19];
    const float* temb  = (const float*)d_in[20];
    const float* Wout  = (const float*)d_in[21];
    const float* bout  = (const float*)d_in[22];

    float* outp = (float*)d_out;
    char*  wsb  = (char*)d_ws;

    float* gates   = (float*)(wsb + OFFB_GATES);
    float* aligned = (float*)(wsb + OFFB_ALIGNED);
    bf16*  wbb     = (bf16*) (wsb + OFFB_WBB);
    bf16*  tmpb    = (bf16*) (wsb + OFFB_TMPB);
    float* H1      = (float*)(wsb + OFFB_H1);
    float* x       = (float*)(wsb + OFFB_X);
    bf16*  xb      = (bf16*) (wsb + OFFB_XB);
    bf16*  rnnb    = (bf16*) (wsb + OFFB_RNNB);
    float* wbuf    = (float*)(wsb + OFFB_W);
    unsigned* bar  = (unsigned*)(wsb + OFFB_BAR);
    bf16*  Wihb    = (bf16*) (wsb + OFFB_WIHB);
    bf16*  Whhb    = (bf16*) (wsb + OFFB_WHHB);
    bf16*  Whkb    = (bf16*) (wsb + OFFB_WHKB);
    bf16*  W1b     = (bf16*) (wsb + OFFB_W1B);
    bf16*  WdTb    = (bf16*) (wsb + OFFB_WDTB);
    float* salpha  = (float*)(wsb + OFFB_SALPHA);
    float* sbeta   = (float*)(wsb + OFFB_SBETA);

    float* pred_out  = outp + 1024;                        // (B,S,D)
    float* noise_out = outp + 1024 + (size_t)Bb * Ss * Dd; // (B,S,D)

    // fused prep: all weight converts + Wdiff transpose + alpha + flag init
    prep_kernel<<<2497, 256, 0, stream>>>(Wih, Wihb, Whh, Whhb, Whk, Whkb,
                                          W1, W1b, Wdiff, WdTb,
                                          tdiff, salpha, sbeta, bar);

    // x = emb[seqs].sum(axis=2)  (fp32 + bf16), wave-per-(b,s) float4
    embed_kernel<<<(Bb * Ss) / 4, 256, 0, stream>>>(seqs, emb, x, xb);

    // gates_pre = x @ Wih^T + bih + bhh : (12800 x 1024), K=256
    mfma_gemm<128, 128, 0><<<dim3(100, 8), 256, 0, stream>>>(
        xb, 256, Wihb, 256, bih, bhh, gates, nullptr, 1024, 256);

    // LSTM recurrence (blocks 0..63, r9 exchange) + pool_x overlay (64..319)
    lstm_quad<<<64 + Bb, 512, 0, stream>>>(Whhb, gates, rnnb, bar,
                                           x, Wout, bout, outp);

    // w = rnn @ Whk^T + bhk : fp32 wbuf + bf16 wbb (feeds fused-cat H1 GEMM)
    mfma_gemm<128, 128, 0><<<dim3(100, 2), 256, 0, stream>>>(
        rnnb, 256, Whkb, 256, bhk, nullptr, wbuf, wbb, 256, 256);

    // H1 = tanh(cat @ W1^T + b1), cat built on the fly from xb/wbb
    h1_gemm<<<dim3(98, 1), 256, 0, stream>>>(xb, wbb, W1b, b1, H1);

    // fused: attn logits+softmax, apply, diffusion elementwise, noise copy
    attn_diff_kernel<<<Bb * Ss, 256, 0, stream>>>(
        x, wbuf, H1, W2, b2, noise, temb, tdiff, salpha, sbeta,
        aligned, tmpb, noise_out);

    // predicted_noise = tmp @ Wdiff + bdiff -> d_out
    mfma_gemm<128, 128, 0><<<dim3(100, 2), 256, 0, stream>>>(
        tmpb, 256, WdTb, 256, bdiff, nullptr, pred_out, nullptr, 256, 256);

    // gen_pool head: max_s(aligned + noise - pred) @ Wout^T + bout
    gen_pool_kernel<<<Bb, 256, 0, stream>>>(aligned, noise, pred_out, Wout, bout, outp + 512);
}

// Round 12
// 423.406 us; speedup vs baseline: 1.2068x; 1.1120x over previous
//
#include <hip/hip_runtime.h>
#include <cmath>

// Problem constants
#define Bb 256
#define Ss 50
#define Cc 40
#define Dd 256
#define Vv 20000

typedef __bf16 bf16;
typedef __bf16 bf16x8 __attribute__((ext_vector_type(8)));
typedef float f32x4 __attribute__((ext_vector_type(4)));
typedef unsigned long long u64;

#define GL2LDS(g, l) __builtin_amdgcn_global_load_lds( \
    (__attribute__((address_space(1))) void*)(g), \
    (__attribute__((address_space(3))) void*)(l), 16, 0, 0)

// ---------------- ws layout (BYTE offsets) ----------------
#define OFFB_GATES    0ull
#define OFFB_WBB      13107200ull
#define OFFB_H1       32505856ull
#define OFFB_X        52428800ull
#define OFFB_XB       65536000ull
#define OFFB_RNNB     72089600ull
#define OFFB_W        78643200ull
#define OFFB_BAR      91750400ull
#define OFFB_WIHB     92012544ull
#define OFFB_WHHB     92536832ull
#define OFFB_WHKB     93061120ull
#define OFFB_W1B      93192192ull
#define OFFB_WDTB     93257728ull
#define OFFB_SALPHA   93388800ull
#define OFFB_SBETA    93389824ull

// ---------------- bf16 MFMA GEMM (optional extra bf16 output Cb) ----------
template<int BM, int BN, int ACT>
__global__ __launch_bounds__(256) void mfma_gemm(
    const bf16* __restrict__ A, int lda,
    const bf16* __restrict__ B, int ldb,
    const float* __restrict__ bias1, const float* __restrict__ bias2,
    float* __restrict__ C, bf16* __restrict__ Cb, int ldc, int K)
{
    constexpr int BK = 32;
    constexpr int NF = BN / 32;           // n-frags per wave (2x2 wave grid)
    __shared__ bf16 As[BM * BK];
    __shared__ bf16 Bs[BN * BK];
    const int tid  = threadIdx.x;
    const int wave = tid >> 6;
    const int lane = tid & 63;
    const int m0 = blockIdx.x * BM;
    const int n0 = blockIdx.y * BN;
    const int wm = (wave >> 1) * 64;      // wave row offset in tile
    const int wn = (wave & 1) * (BN / 2); // wave col offset in tile

    f32x4 acc[4][NF];
#pragma unroll
    for (int i = 0; i < 4; ++i)
#pragma unroll
        for (int j = 0; j < NF; ++j) acc[i][j] = (f32x4){0.f, 0.f, 0.f, 0.f};

    const int ar = tid >> 2;              // staging row (0..63) within iter
    const int ac = tid & 3;               // staging chunk
    const int sw = ac ^ (ar & 3);         // swizzled source chunk
    const int lr = lane & 15;
    const int q  = lane >> 4;             // k-chunk of fragment

    for (int k0 = 0; k0 < K; k0 += BK) {
        __syncthreads();
#pragma unroll
        for (int it = 0; it < BM / 64; ++it) {
            const bf16* gp = A + (size_t)(m0 + it * 64 + ar) * lda + k0 + sw * 8;
            GL2LDS(gp, As + it * 2048 + wave * 512);
        }
#pragma unroll
        for (int it = 0; it < BN / 64; ++it) {
            const bf16* gp = B + (size_t)(n0 + it * 64 + ar) * ldb + k0 + sw * 8;
            GL2LDS(gp, Bs + it * 2048 + wave * 512);
        }
        __syncthreads();

        bf16x8 af[4], bfv[NF];
#pragma unroll
        for (int fm = 0; fm < 4; ++fm) {
            int m = wm + fm * 16 + lr;
            af[fm] = *(const bf16x8*)(As + m * 32 + ((q ^ (m & 3)) * 8));
        }
#pragma unroll
        for (int fn = 0; fn < NF; ++fn) {
            int n = wn + fn * 16 + lr;
            bfv[fn] = *(const bf16x8*)(Bs + n * 32 + ((q ^ (n & 3)) * 8));
        }
#pragma unroll
        for (int fm = 0; fm < 4; ++fm)
#pragma unroll
            for (int fn = 0; fn < NF; ++fn)
                acc[fm][fn] = __builtin_amdgcn_mfma_f32_16x16x32_bf16(
                    af[fm], bfv[fn], acc[fm][fn], 0, 0, 0);
    }

    // epilogue: C/D layout col=lane&15, row=(lane>>4)*4+reg
    const int rbase = q * 4;
#pragma unroll
    for (int fn = 0; fn < NF; ++fn) {
        const int col = n0 + wn + fn * 16 + lr;
        float bb = 0.f;
        if (bias1) bb += bias1[col];
        if (bias2) bb += bias2[col];
#pragma unroll
        for (int fm = 0; fm < 4; ++fm) {
            f32x4 v = acc[fm][fn];
#pragma unroll
            for (int r = 0; r < 4; ++r) {
                const int row = m0 + wm + fm * 16 + rbase + r;
                float val = v[r] + bb;
                if (ACT == 1) val = tanhf(val);
                C[(size_t)row * ldc + col] = val;
                if (Cb) Cb[(size_t)row * ldc + col] = (bf16)val;
            }
        }
    }
}

// ---------------- H1 GEMM with fused cat construction ----------------------
__global__ __launch_bounds__(256) void h1_gemm(
    const bf16* __restrict__ xb, const bf16* __restrict__ wbb,
    const bf16* __restrict__ W1b,
    const float* __restrict__ b1, float* __restrict__ H1)
{
    constexpr int BM = 128, BN = 64, BK = 32, NF = 2;
    constexpr int K = 512;
    __shared__ bf16 As[BM * BK];
    __shared__ bf16 Bs[BN * BK];
    const int tid  = threadIdx.x;
    const int wave = tid >> 6;
    const int lane = tid & 63;
    const int m0 = blockIdx.x * BM;
    const int wm = (wave >> 1) * 64;
    const int wn = (wave & 1) * 32;

    f32x4 acc[4][NF];
#pragma unroll
    for (int i = 0; i < 4; ++i)
#pragma unroll
        for (int j = 0; j < NF; ++j) acc[i][j] = (f32x4){0.f, 0.f, 0.f, 0.f};

    const int ar = tid >> 2;
    const int ac = tid & 3;
    const int sw = ac ^ (ar & 3);
    const int lr = lane & 15;
    const int q  = lane >> 4;

    for (int k0 = 0; k0 < K; k0 += BK) {
        __syncthreads();
#pragma unroll
        for (int it = 0; it < 2; ++it) {
            const int row = m0 + it * 64 + ar;
            const int b = row / (Ss - 1), t = row - b * (Ss - 1);
            const int col = k0 + sw * 8;
            const bf16* gp = (col < 256)
                ? xb  + (size_t)b * (Ss * Dd) + col
                : wbb + ((size_t)(b * Ss + t)) * Dd + (col - 256);
            GL2LDS(gp, As + it * 2048 + wave * 512);
        }
        {
            const bf16* gp = W1b + (size_t)ar * K + k0 + sw * 8;
            GL2LDS(gp, Bs + wave * 512);
        }
        __syncthreads();

        bf16x8 af[4], bfv[NF];
#pragma unroll
        for (int fm = 0; fm < 4; ++fm) {
            int m = wm + fm * 16 + lr;
            af[fm] = *(const bf16x8*)(As + m * 32 + ((q ^ (m & 3)) * 8));
        }
#pragma unroll
        for (int fn = 0; fn < NF; ++fn) {
            int n = wn + fn * 16 + lr;
            bfv[fn] = *(const bf16x8*)(Bs + n * 32 + ((q ^ (n & 3)) * 8));
        }
#pragma unroll
        for (int fm = 0; fm < 4; ++fm)
#pragma unroll
            for (int fn = 0; fn < NF; ++fn)
                acc[fm][fn] = __builtin_amdgcn_mfma_f32_16x16x32_bf16(
                    af[fm], bfv[fn], acc[fm][fn], 0, 0, 0);
    }

    const int rbase = q * 4;
#pragma unroll
    for (int fn = 0; fn < NF; ++fn) {
        const int col = wn + fn * 16 + lr;
        const float bb = b1[col];
#pragma unroll
        for (int fm = 0; fm < 4; ++fm) {
            f32x4 v = acc[fm][fn];
#pragma unroll
            for (int r = 0; r < 4; ++r) {
                const int row = m0 + wm + fm * 16 + rbase + r;
                H1[(size_t)row * 64 + col] = tanhf(v[r] + bb);
            }
        }
    }
}

// ---------------- fused LSTM recurrence (r9 exchange) + pool_x overlay -----
// Blocks 0..63: recurrence (r9's measured-best protocol). Blocks 64..319:
// pool_x head on the idle CUs. Unchanged from r11 (best measured).
__global__ __launch_bounds__(512, 2) void lstm_quad(
    const bf16* __restrict__ Whhb,    // (1024 x 256) N x K
    const float* __restrict__ gates,  // (B*S x 1024) x@Wih^T+bih+bhh
    bf16* __restrict__ rnnb,          // (B*S x 256) h outputs + exchange
    unsigned* __restrict__ bar,       // flags: bar[(bm*4+bd)*32]
    const float* __restrict__ xf,     // (B*S x 256) fp32 x (pool input)
    const float* __restrict__ Wout, const float* __restrict__ bout,
    float* __restrict__ outp)
{
    if (blockIdx.x >= 64) {
        // ---- pool_x overlay: max_s x[b,s,:] @ Wout^T + bout ----
        __shared__ float r0[4], r1[4];
        const int b = blockIdx.x - 64;
        const int tid = threadIdx.x;
        if (tid < 256) {
            float m = -INFINITY;
            for (int s = 0; s < Ss; ++s)
                m = fmaxf(m, xf[((size_t)b * Ss + s) * Dd + tid]);
            float v0 = m * Wout[tid];
            float v1 = m * Wout[Dd + tid];
#pragma unroll
            for (int off = 32; off; off >>= 1) {
                v0 += __shfl_down(v0, off);
                v1 += __shfl_down(v1, off);
            }
            if ((tid & 63) == 0) { r0[tid >> 6] = v0; r1[tid >> 6] = v1; }
        }
        __syncthreads();
        if (tid == 0) {
            outp[b * 2 + 0] = r0[0] + r0[1] + r0[2] + r0[3] + bout[0];
            outp[b * 2 + 1] = r1[0] + r1[1] + r1[2] + r1[3] + bout[1];
        }
        return;
    }

    __shared__ bf16 hb0[16 * 256];
    __shared__ bf16 hb1[16 * 256];
    __shared__ float pacc[4][4][16][17];
    const int tid  = threadIdx.x;
    const int w    = tid >> 6;
    const int lane = tid & 63;
    const int lr   = lane & 15;
    const int q    = lane >> 4;
    const int bm   = blockIdx.x & 15;
    const int bd   = blockIdx.x >> 4;       // 0..3
    const int kh   = w >> 2;                // K-half
    const int ct   = w & 3;                 // col tile
    const int dg   = bd * 64 + ct * 16 + lr;

    // ---- loop-invariant Whh fragments for this K-half: 64 VGPR ----
    f32x4 wfr[4][4];
#pragma unroll
    for (int g = 0; g < 4; ++g) {
        const bf16* brow = Whhb + (size_t)(g * 256 + dg) * Dd + kh * 128 + q * 8;
#pragma unroll
        for (int kc = 0; kc < 4; ++kc)
            wfr[g][kc] = *(const f32x4*)(brow + kc * 32);
    }

    // gate-preact pointers (kh=0 lanes): rows q*4+r, col dg
    const float* gp[4];
#pragma unroll
    for (int r = 0; r < 4; ++r)
        gp[r] = gates + (size_t)(bm * 16 + q * 4 + r) * (Ss * 1024) + dg;

    // pack/store role (tid < 256): 8 B = 4 cols of one row
    const int xrow = tid >> 4, xc8 = tid & 15;
    const size_t my_base = ((size_t)(bm * 16 + xrow) * Ss) * Dd + bd * 64 + xc8 * 4;
    const int pack_off = xrow * 512 + (((bd * 8 + (xc8 >> 1)) ^ (xrow & 7)) << 4) + (xc8 & 1) * 8;

    // remote-load slots: slot A (all 512 threads), slot B (tid < 256)
    const int pA  = tid >> 8;                         // 0 or 1
    const int pdA = pA + (pA >= bd ? 1 : 0);
    const int pdB = 2 + (2 >= bd ? 1 : 0);
    const int rowA = (tid >> 4) & 15, xqA = tid & 15;
    const size_t gA = ((size_t)(bm * 16 + rowA) * Ss) * Dd + pdA * 64 + xqA * 4;
    const size_t gB = ((size_t)(bm * 16 + xrow) * Ss) * Dd + pdB * 64 + xc8 * 4;
    const int unpA = rowA * 512 + (((pdA * 8 + (xqA >> 1)) ^ (rowA & 7)) << 4) + (xqA & 1) * 8;
    const int unpB = xrow * 512 + (((pdB * 8 + (xc8 >> 1)) ^ (xrow & 7)) << 4) + (xc8 & 1) * 8;
    unsigned* myf = bar + (bm * 4 + bd) * 32;
    unsigned* pfA = bar + (bm * 4 + pdA) * 32;
    unsigned* pfB = bar + (bm * 4 + pdB) * 32;

    // elementwise LDS write offsets (kh=0 lanes): row q*4+r, col dg
    int ew_off[4];
#pragma unroll
    for (int r = 0; r < 4; ++r) {
        const int row = q * 4 + r;
        ew_off[r] = row * 512 + (((dg >> 3) ^ (row & 7)) << 4) + (dg & 7) * 2;
    }

    float c[4] = {0.f, 0.f, 0.f, 0.f};
    float gaA[4][4], gaB[4][4];   // [gate][r], double-buffered preacts
    if (kh == 0) {
#pragma unroll
        for (int r = 0; r < 4; ++r)
#pragma unroll
            for (int g = 0; g < 4; ++g) gaA[g][r] = gp[r][g * 256];
    }

#define STEP(T, GACUR, GANEXT, RD, WR, FIRST)                                   \
    {                                                                           \
        f32x4 acc[4];                                                           \
        _Pragma("unroll")                                                       \
        for (int g = 0; g < 4; ++g) acc[g] = (f32x4){0.f, 0.f, 0.f, 0.f};       \
        if (!(FIRST)) {                                                         \
            bf16x8 af[4];                                                       \
            _Pragma("unroll")                                                   \
            for (int kc = 0; kc < 4; ++kc)                                      \
                af[kc] = *(const bf16x8*)((const char*)(RD) + lr * 512          \
                         + (((kh * 16 + kc * 4 + q) ^ (lr & 7)) << 4));         \
            _Pragma("unroll")                                                   \
            for (int kc = 0; kc < 4; ++kc)                                      \
                _Pragma("unroll")                                               \
                for (int g = 0; g < 4; ++g)                                     \
                    acc[g] = __builtin_amdgcn_mfma_f32_16x16x32_bf16(           \
                        af[kc], __builtin_bit_cast(bf16x8, wfr[g][kc]),         \
                        acc[g], 0, 0, 0);                                       \
        }                                                                       \
        if (kh == 1) {                                                          \
            _Pragma("unroll")                                                   \
            for (int g = 0; g < 4; ++g)                                         \
                _Pragma("unroll")                                               \
                for (int r = 0; r < 4; ++r)                                     \
                    pacc[ct][g][q * 4 + r][lr] = acc[g][r];                     \
        }                                                                       \
        __syncthreads();  /* Ba: kh1 partials visible */                        \
        if (kh == 0) {                                                          \
            _Pragma("unroll")                                                   \
            for (int r = 0; r < 4; ++r) {                                       \
                float gi = acc[0][r] + pacc[ct][0][q * 4 + r][lr] + GACUR[0][r];\
                float gf = acc[1][r] + pacc[ct][1][q * 4 + r][lr] + GACUR[1][r];\
                float gg = acc[2][r] + pacc[ct][2][q * 4 + r][lr] + GACUR[2][r];\
                float go = acc[3][r] + pacc[ct][3][q * 4 + r][lr] + GACUR[3][r];\
                float ii  = 1.f / (1.f + expf(-gi));                            \
                float ff  = 1.f / (1.f + expf(-gf));                            \
                float g2t = tanhf(gg);                                          \
                float oo  = 1.f / (1.f + expf(-go));                            \
                c[r] = ff * c[r] + ii * g2t;                                    \
                *(bf16*)((char*)(WR) + ew_off[r]) = (bf16)(oo * tanhf(c[r]));   \
            }                                                                   \
        }                                                                       \
        __syncthreads();  /* B1: local h slice in LDS */                        \
        if (tid < 256) {                                                        \
            u64 v = *(const u64*)((const char*)(WR) + pack_off);                \
            __hip_atomic_store((u64*)(rnnb + my_base + (size_t)(T) * Dd), v,    \
                               __ATOMIC_RELAXED, __HIP_MEMORY_SCOPE_AGENT);     \
        }                                                                       \
        if ((T) != Ss - 1) {                                                    \
            __syncthreads();  /* B2: per-wave vmcnt(0) -> stores at LLC */      \
            if (tid == 0)                                                       \
                __hip_atomic_store(myf, (unsigned)((T) + 1),                    \
                                   __ATOMIC_RELAXED, __HIP_MEMORY_SCOPE_AGENT); \
            if (kh == 0) {  /* preact prefetch hides under exchange */          \
                _Pragma("unroll")                                               \
                for (int r = 0; r < 4; ++r)                                     \
                    _Pragma("unroll")                                           \
                    for (int g = 0; g < 4; ++g)                                 \
                        GANEXT[g][r] = gp[r][(size_t)((T) + 1) * 1024 + g * 256];\
            }                                                                   \
            while (__hip_atomic_load(pfA, __ATOMIC_RELAXED,                     \
                                     __HIP_MEMORY_SCOPE_AGENT)                  \
                   < (unsigned)((T) + 1)) {}                                    \
            {                                                                   \
                u64 rv = __hip_atomic_load(                                     \
                    (const u64*)(rnnb + gA + (size_t)(T) * Dd),                 \
                    __ATOMIC_RELAXED, __HIP_MEMORY_SCOPE_AGENT);                \
                *(u64*)((char*)(WR) + unpA) = rv;                               \
            }                                                                   \
            if (tid < 256) {                                                    \
                while (__hip_atomic_load(pfB, __ATOMIC_RELAXED,                 \
                                         __HIP_MEMORY_SCOPE_AGENT)              \
                       < (unsigned)((T) + 1)) {}                                \
                u64 rv = __hip_atomic_load(                                     \
                    (const u64*)(rnnb + gB + (size_t)(T) * Dd),                 \
                    __ATOMIC_RELAXED, __HIP_MEMORY_SCOPE_AGENT);                \
                *(u64*)((char*)(WR) + unpB) = rv;                               \
            }                                                                   \
            __syncthreads();  /* B4: full h_t (local+3 remote) in WR */         \
        }                                                                       \
    }

    for (int t2 = 0; t2 < Ss; t2 += 2) {
        STEP(t2,     gaA, gaB, hb1, hb0, (t2 == 0));
        STEP(t2 + 1, gaB, gaA, hb0, hb1, false);
    }
#undef STEP
}

// ---------------- fused prep: converts + transpose + alpha + EMBED ---------
// Blocks: [0,1024) Wih | [1024,2048) Whh | [2048,2304) Whk | [2304,2432) W1 |
// [2432,2496) Wdiff transpose | 2496 alpha+flags | [2497,5697) embed
__global__ __launch_bounds__(256) void prep_kernel(
    const float* __restrict__ Wih, bf16* __restrict__ Wihb,
    const float* __restrict__ Whh, bf16* __restrict__ Whhb,
    const float* __restrict__ Whk, bf16* __restrict__ Whkb,
    const float* __restrict__ W1,  bf16* __restrict__ W1b,
    const float* __restrict__ Wdiff, bf16* __restrict__ WdTb,
    const int* __restrict__ tdiff, float* __restrict__ salpha,
    float* __restrict__ sbeta, unsigned* __restrict__ bar,
    const int* __restrict__ seqs, const float* __restrict__ emb,
    float* __restrict__ x, bf16* __restrict__ xb)
{
    __shared__ float t[32][33];
    __shared__ int idx[4][Cc];
    int bx = blockIdx.x;
    const int tid = threadIdx.x;
    if (bx < 1024) { int i = bx * 256 + tid; Wihb[i] = (bf16)Wih[i]; return; }
    bx -= 1024;
    if (bx < 1024) { int i = bx * 256 + tid; Whhb[i] = (bf16)Whh[i]; return; }
    bx -= 1024;
    if (bx < 256)  { int i = bx * 256 + tid; Whkb[i] = (bf16)Whk[i]; return; }
    bx -= 256;
    if (bx < 128)  { int i = bx * 256 + tid; W1b[i]  = (bf16)W1[i];  return; }
    bx -= 128;
    if (bx < 64) {
        const int c0 = (bx & 7) * 32, r0 = (bx >> 3) * 32;
        const int tx = tid & 31, ty = tid >> 5;
        for (int i = ty; i < 32; i += 8)
            t[i][tx] = Wdiff[(size_t)(r0 + i) * 256 + c0 + tx];
        __syncthreads();
        for (int i = ty; i < 32; i += 8)
            WdTb[(size_t)(c0 + i) * 256 + r0 + tx] = (bf16)t[tx][i];
        return;
    }
    bx -= 64;
    if (bx == 0) {
        // alpha + barrier-flag init
#pragma unroll
        for (int j = 0; j < 8; ++j) bar[tid * 8 + j] = 0u;
        const int tt = tdiff[tid];
        const float step = (0.02f - 1e-4f) / 999.f;
        float prod = 1.f;
        for (int j = 0; j <= tt; ++j) prod *= (1.f - (1e-4f + j * step));
        salpha[tid] = sqrtf(prod);
        sbeta[tid]  = sqrtf(fmaxf(1.f - prod, 0.f));
        return;
    }
    bx -= 1;
    // embed: wave-per-(b,s), float4 gathers (bx in [0,3200))
    const int w = tid >> 6, l = tid & 63;
    const int bs0 = bx * 4;
    if (tid < 4 * Cc) idx[tid / Cc][tid % Cc] = seqs[(size_t)bs0 * Cc + tid];
    __syncthreads();
    f32x4 s = (f32x4){0.f, 0.f, 0.f, 0.f};
#pragma unroll 8
    for (int c = 0; c < Cc; ++c)
        s += *(const f32x4*)(emb + (size_t)idx[w][c] * Dd + l * 4);
    const size_t o = (size_t)(bs0 + w) * Dd + l * 4;
    *(f32x4*)(x + o) = s;
    bf16 b4[4] = {(bf16)s[0], (bf16)s[1], (bf16)s[2], (bf16)s[3]};
    *(u64*)(xb + o) = *(const u64*)b4;
}

// ---------------- tail: attn softmax+apply + diffusion + pred GEMM + pool --
// One block per batch b (256 blocks x 256 threads = 4 waves).
// Phase 0: softmax coeffs (bit-identical 64-lane reduce to old attn2).
// Phase 1: aligned rows -> LDS fp32 (never global); tmpb built DIRECTLY into
//          a swizzled LDS A-tile (same XOR pair as the verified lstm hb
//          buffers); noise passthrough fused here.
// Phase 2: pred = tmpb @ WdTb^T (M=64pad, N=256, K=256), B staged per
//          K-chunk via GL2LDS (proven mfma_gemm pattern).
// Phase 3: epilogue writes pred (row<50), computes gen = aligned+noise-pred,
//          in-register cross-row max (shfl_xor 16/32), pooled 2-class head.
__global__ __launch_bounds__(256) void tail_kernel(
    const float* __restrict__ x, const float* __restrict__ wbuf,
    const float* __restrict__ H1, const float* __restrict__ W2,
    const float* __restrict__ b2, const float* __restrict__ noise,
    const float* __restrict__ temb, const int* __restrict__ tdiff,
    const float* __restrict__ salpha, const float* __restrict__ sbeta,
    const bf16* __restrict__ WdTb, const float* __restrict__ bdiff,
    const float* __restrict__ Wout, const float* __restrict__ bout,
    float* __restrict__ pred_out, float* __restrict__ noise_out,
    float* __restrict__ outp_gen)
{
    __shared__ float alignedL[Ss * 256];   // 51.2 KB fp32
    __shared__ bf16  tmpbL[64 * 256];      // 32 KB swizzled A-tile
    __shared__ bf16  Bs[256 * 32];         // 16 KB B K-chunk
    __shared__ float saL[Ss - 1][2];
    __shared__ float rr0[4], rr1[4];

    const int b    = blockIdx.x;
    const int tid  = threadIdx.x;
    const int wave = tid >> 6;
    const int lane = tid & 63;
    const int lr   = lane & 15;
    const int q    = lane >> 4;

    // ---- Phase 0: softmax coefficients ----
    for (int t = wave; t < Ss - 1; t += 4) {
        const int r = b * (Ss - 1) + t;
        float h = H1[(size_t)r * 64 + lane];
        float v0 = h * W2[lane];
        float v1 = h * W2[64 + lane];
#pragma unroll
        for (int off = 32; off; off >>= 1) { v0 += __shfl_down(v0, off); v1 += __shfl_down(v1, off); }
        if (lane == 0) {
            float z0 = v0 + b2[0], z1 = v1 + b2[1];
            float m = fmaxf(z0, z1);
            float e0 = expf(z0 - m), e1 = expf(z1 - m);
            float inv = 1.f / (e0 + e1);
            saL[t][0] = e0 * inv;
            saL[t][1] = e1 * inv;
        }
    }
    __syncthreads();

    // ---- Phase 1: aligned + tmpb (LDS) + noise passthrough ----
    {
        const int d = tid;
        const float ek = x[((size_t)b * Ss) * Dd + d];
        const int tt = tdiff[b];
        const float sa_ = salpha[b], sb_ = sbeta[b];
        const float te = temb[(size_t)tt * Dd + d];
        for (int s = 0; s < Ss; ++s) {
            float v;
            if (s == 0) v = ek;
            else v = ek * saL[s - 1][0]
                   + wbuf[((size_t)b * Ss + s - 1) * Dd + d] * saL[s - 1][1];
            alignedL[s * 256 + d] = v;
            const size_t i = ((size_t)b * Ss + s) * Dd + d;
            const float nz = noise[i];
            noise_out[i] = nz;
            const int off = s * 512 + (((d >> 3) ^ (s & 7)) << 4) + (d & 7) * 2;
            *(bf16*)((char*)tmpbL + off) = (bf16)(v * sa_ + nz * sb_ + te);
        }
#pragma unroll
        for (int s = Ss; s < 64; ++s) {   // zero pad rows
            const int off = s * 512 + (((d >> 3) ^ (s & 7)) << 4) + (d & 7) * 2;
            *(bf16*)((char*)tmpbL + off) = (bf16)0.f;
        }
    }

    // ---- Phase 2: pred GEMM (M=64, N=256, K=256) ----
    f32x4 acc[4][4];
#pragma unroll
    for (int i = 0; i < 4; ++i)
#pragma unroll
        for (int j = 0; j < 4; ++j) acc[i][j] = (f32x4){0.f, 0.f, 0.f, 0.f};

    const int ar = tid >> 2, ac = tid & 3, sw = ac ^ (ar & 3);
    const int wn = wave * 64;

    for (int k0 = 0; k0 < 256; k0 += 32) {
        __syncthreads();
#pragma unroll
        for (int it = 0; it < 4; ++it) {
            const bf16* gp2 = WdTb + (size_t)(it * 64 + ar) * 256 + k0 + sw * 8;
            GL2LDS(gp2, Bs + it * 2048 + wave * 512);
        }
        __syncthreads();
        bf16x8 af[4], bfv[4];
#pragma unroll
        for (int fm = 0; fm < 4; ++fm) {
            const int m = fm * 16 + lr;
            af[fm] = *(const bf16x8*)((const char*)tmpbL + m * 512
                      + ((((k0 >> 3) + q) ^ (m & 7)) << 4));
        }
#pragma unroll
        for (int fn = 0; fn < 4; ++fn) {
            const int n = wn + fn * 16 + lr;
            bfv[fn] = *(const bf16x8*)(Bs + n * 32 + ((q ^ (n & 3)) * 8));
        }
#pragma unroll
        for (int fm = 0; fm < 4; ++fm)
#pragma unroll
            for (int fn = 0; fn < 4; ++fn)
                acc[fm][fn] = __builtin_amdgcn_mfma_f32_16x16x32_bf16(
                    af[fm], bfv[fn], acc[fm][fn], 0, 0, 0);
    }

    // ---- Phase 3: pred write + gen max + pooled head ----
    float v0 = 0.f, v1 = 0.f;
#pragma unroll
    for (int fn = 0; fn < 4; ++fn) {
        const int col = wn + fn * 16 + lr;
        const float bd_ = bdiff[col];
        float mx = -INFINITY;
#pragma unroll
        for (int fm = 0; fm < 4; ++fm) {
#pragma unroll
            for (int r = 0; r < 4; ++r) {
                const int row = fm * 16 + q * 4 + r;
                if (row < Ss) {
                    const float pred = acc[fm][fn][r] + bd_;
                    const size_t i = ((size_t)b * Ss + row) * Dd + col;
                    pred_out[i] = pred;
                    const float gen = alignedL[row * 256 + col] + noise[i] - pred;
                    mx = fmaxf(mx, gen);
                }
            }
        }
        mx = fmaxf(mx, __shfl_xor(mx, 16));
        mx = fmaxf(mx, __shfl_xor(mx, 32));
        if (q == 0) { v0 += mx * Wout[col]; v1 += mx * Wout[Dd + col]; }
    }
#pragma unroll
    for (int off = 32; off; off >>= 1) { v0 += __shfl_down(v0, off); v1 += __shfl_down(v1, off); }
    if (lane == 0) { rr0[wave] = v0; rr1[wave] = v1; }
    __syncthreads();
    if (tid == 0) {
        outp_gen[b * 2 + 0] = rr0[0] + rr0[1] + rr0[2] + rr0[3] + bout[0];
        outp_gen[b * 2 + 1] = rr1[0] + rr1[1] + rr1[2] + rr1[3] + bout[1];
    }
}

// ---------------- host ----------------
extern "C" void kernel_launch(void* const* d_in, const int* in_sizes, int n_in,
                              void* d_out, int out_size, void* d_ws, size_t ws_size,
                              hipStream_t stream)
{
    const int*   seqs  = (const int*)d_in[0];
    const int*   tdiff = (const int*)d_in[5];
    const float* noise = (const float*)d_in[6];
    const float* emb   = (const float*)d_in[7];
    const float* Wih   = (const float*)d_in[8];
    const float* Whh   = (const float*)d_in[9];
    const float* bih   = (const float*)d_in[10];
    const float* bhh   = (const float*)d_in[11];
    const float* Whk   = (const float*)d_in[12];
    const float* bhk   = (const float*)d_in[13];
    const float* W1    = (const float*)d_in[14];
    const float* b1    = (const float*)d_in[15];
    const float* W2    = (const float*)d_in[16];
    const float* b2    = (const float*)d_in[17];
    const float* Wdiff = (const float*)d_in[18];
    const float* bdiff = (const float*)d_in[19];
    const float* temb  = (const float*)d_in[20];
    const float* Wout  = (const float*)d_in[21];
    const float* bout  = (const float*)d_in[22];

    float* outp = (float*)d_out;
    char*  wsb  = (char*)d_ws;

    float* gates   = (float*)(wsb + OFFB_GATES);
    bf16*  wbb     = (bf16*) (wsb + OFFB_WBB);
    float* H1      = (float*)(wsb + OFFB_H1);
    float* x       = (float*)(wsb + OFFB_X);
    bf16*  xb      = (bf16*) (wsb + OFFB_XB);
    bf16*  rnnb    = (bf16*) (wsb + OFFB_RNNB);
    float* wbuf    = (float*)(wsb + OFFB_W);
    unsigned* bar  = (unsigned*)(wsb + OFFB_BAR);
    bf16*  Wihb    = (bf16*) (wsb + OFFB_WIHB);
    bf16*  Whhb    = (bf16*) (wsb + OFFB_WHHB);
    bf16*  Whkb    = (bf16*) (wsb + OFFB_WHKB);
    bf16*  W1b     = (bf16*) (wsb + OFFB_W1B);
    bf16*  WdTb    = (bf16*) (wsb + OFFB_WDTB);
    float* salpha  = (float*)(wsb + OFFB_SALPHA);
    float* sbeta   = (float*)(wsb + OFFB_SBETA);

    float* pred_out  = outp + 1024;                        // (B,S,D)
    float* noise_out = outp + 1024 + (size_t)Bb * Ss * Dd; // (B,S,D)

    // fused prep: weight converts + transpose + alpha + flags + EMBED
    prep_kernel<<<5697, 256, 0, stream>>>(Wih, Wihb, Whh, Whhb, Whk, Whkb,
                                          W1, W1b, Wdiff, WdTb,
                                          tdiff, salpha, sbeta, bar,
                                          seqs, emb, x, xb);

    // gates_pre = x @ Wih^T + bih + bhh : (12800 x 1024), K=256
    mfma_gemm<128, 128, 0><<<dim3(100, 8), 256, 0, stream>>>(
        xb, 256, Wihb, 256, bih, bhh, gates, nullptr, 1024, 256);

    // LSTM recurrence (blocks 0..63, r9 exchange) + pool_x overlay (64..319)
    lstm_quad<<<64 + Bb, 512, 0, stream>>>(Whhb, gates, rnnb, bar,
                                           x, Wout, bout, outp);

    // w = rnn @ Whk^T + bhk : fp32 wbuf + bf16 wbb (feeds fused-cat H1 GEMM)
    mfma_gemm<128, 128, 0><<<dim3(100, 2), 256, 0, stream>>>(
        rnnb, 256, Whkb, 256, bhk, nullptr, wbuf, wbb, 256, 256);

    // H1 = tanh(cat @ W1^T + b1), cat built on the fly from xb/wbb
    h1_gemm<<<dim3(98, 1), 256, 0, stream>>>(xb, wbb, W1b, b1, H1);

    // tail: attn softmax+apply + diffusion + pred GEMM + gen_pool + noise copy
    tail_kernel<<<Bb, 256, 0, stream>>>(
        x, wbuf, H1, W2, b2, noise, temb, tdiff, salpha, sbeta,
        WdTb, bdiff, Wout, bout, pred_out, noise_out, outp + 512);
}

// Round 13
// 404.184 us; speedup vs baseline: 1.2642x; 1.0476x over previous
//
#include <hip/hip_runtime.h>
#include <cmath>

// Problem constants
#define Bb 256
#define Ss 50
#define Cc 40
#define Dd 256
#define Vv 20000

typedef __bf16 bf16;
typedef __bf16 bf16x8 __attribute__((ext_vector_type(8)));
typedef float f32x4 __attribute__((ext_vector_type(4)));
typedef unsigned long long u64;

#define GL2LDS(g, l) __builtin_amdgcn_global_load_lds( \
    (__attribute__((address_space(1))) void*)(g), \
    (__attribute__((address_space(3))) void*)(l), 16, 0, 0)

// ---------------- ws layout (BYTE offsets) ----------------
#define OFFB_GATES    0ull
#define OFFB_X        52428800ull
#define OFFB_XB       65536000ull
#define OFFB_RNNB     72089600ull
#define OFFB_BAR      91750400ull
#define OFFB_WIHB     92012544ull
#define OFFB_WHHB     92536832ull
#define OFFB_WHKB     93061120ull
#define OFFB_W1B      93192192ull
#define OFFB_WDTB     93257728ull
#define OFFB_SALPHA   93388800ull
#define OFFB_SBETA    93389824ull

// ---------------- bf16 MFMA GEMM (gates only now) ----------
template<int BM, int BN, int ACT>
__global__ __launch_bounds__(256) void mfma_gemm(
    const bf16* __restrict__ A, int lda,
    const bf16* __restrict__ B, int ldb,
    const float* __restrict__ bias1, const float* __restrict__ bias2,
    float* __restrict__ C, int ldc, int K)
{
    constexpr int BK = 32;
    constexpr int NF = BN / 32;           // n-frags per wave (2x2 wave grid)
    __shared__ bf16 As[BM * BK];
    __shared__ bf16 Bs[BN * BK];
    const int tid  = threadIdx.x;
    const int wave = tid >> 6;
    const int lane = tid & 63;
    const int m0 = blockIdx.x * BM;
    const int n0 = blockIdx.y * BN;
    const int wm = (wave >> 1) * 64;      // wave row offset in tile
    const int wn = (wave & 1) * (BN / 2); // wave col offset in tile

    f32x4 acc[4][NF];
#pragma unroll
    for (int i = 0; i < 4; ++i)
#pragma unroll
        for (int j = 0; j < NF; ++j) acc[i][j] = (f32x4){0.f, 0.f, 0.f, 0.f};

    const int ar = tid >> 2;              // staging row (0..63) within iter
    const int ac = tid & 3;               // staging chunk
    const int sw = ac ^ (ar & 3);         // swizzled source chunk
    const int lr = lane & 15;
    const int q  = lane >> 4;             // k-chunk of fragment

    for (int k0 = 0; k0 < K; k0 += BK) {
        __syncthreads();
#pragma unroll
        for (int it = 0; it < BM / 64; ++it) {
            const bf16* gp = A + (size_t)(m0 + it * 64 + ar) * lda + k0 + sw * 8;
            GL2LDS(gp, As + it * 2048 + wave * 512);
        }
#pragma unroll
        for (int it = 0; it < BN / 64; ++it) {
            const bf16* gp = B + (size_t)(n0 + it * 64 + ar) * ldb + k0 + sw * 8;
            GL2LDS(gp, Bs + it * 2048 + wave * 512);
        }
        __syncthreads();

        bf16x8 af[4], bfv[NF];
#pragma unroll
        for (int fm = 0; fm < 4; ++fm) {
            int m = wm + fm * 16 + lr;
            af[fm] = *(const bf16x8*)(As + m * 32 + ((q ^ (m & 3)) * 8));
        }
#pragma unroll
        for (int fn = 0; fn < NF; ++fn) {
            int n = wn + fn * 16 + lr;
            bfv[fn] = *(const bf16x8*)(Bs + n * 32 + ((q ^ (n & 3)) * 8));
        }
#pragma unroll
        for (int fm = 0; fm < 4; ++fm)
#pragma unroll
            for (int fn = 0; fn < NF; ++fn)
                acc[fm][fn] = __builtin_amdgcn_mfma_f32_16x16x32_bf16(
                    af[fm], bfv[fn], acc[fm][fn], 0, 0, 0);
    }

    // epilogue: C/D layout col=lane&15, row=(lane>>4)*4+reg
    const int rbase = q * 4;
#pragma unroll
    for (int fn = 0; fn < NF; ++fn) {
        const int col = n0 + wn + fn * 16 + lr;
        float bb = 0.f;
        if (bias1) bb += bias1[col];
        if (bias2) bb += bias2[col];
#pragma unroll
        for (int fm = 0; fm < 4; ++fm) {
            f32x4 v = acc[fm][fn];
#pragma unroll
            for (int r = 0; r < 4; ++r) {
                const int row = m0 + wm + fm * 16 + rbase + r;
                float val = v[r] + bb;
                if (ACT == 1) val = tanhf(val);
                C[(size_t)row * ldc + col] = val;
            }
        }
    }
}

// ---------------- fused LSTM recurrence (r9 exchange) + pool_x overlay -----
// Blocks 0..63: recurrence (r9's measured-best protocol). Blocks 64..319:
// pool_x head on the idle CUs. Unchanged from r12 (best measured).
__global__ __launch_bounds__(512, 2) void lstm_quad(
    const bf16* __restrict__ Whhb,    // (1024 x 256) N x K
    const float* __restrict__ gates,  // (B*S x 1024) x@Wih^T+bih+bhh
    bf16* __restrict__ rnnb,          // (B*S x 256) h outputs + exchange
    unsigned* __restrict__ bar,       // flags: bar[(bm*4+bd)*32]
    const float* __restrict__ xf,     // (B*S x 256) fp32 x (pool input)
    const float* __restrict__ Wout, const float* __restrict__ bout,
    float* __restrict__ outp)
{
    if (blockIdx.x >= 64) {
        // ---- pool_x overlay: max_s x[b,s,:] @ Wout^T + bout ----
        __shared__ float r0[4], r1[4];
        const int b = blockIdx.x - 64;
        const int tid = threadIdx.x;
        if (tid < 256) {
            float m = -INFINITY;
            for (int s = 0; s < Ss; ++s)
                m = fmaxf(m, xf[((size_t)b * Ss + s) * Dd + tid]);
            float v0 = m * Wout[tid];
            float v1 = m * Wout[Dd + tid];
#pragma unroll
            for (int off = 32; off; off >>= 1) {
                v0 += __shfl_down(v0, off);
                v1 += __shfl_down(v1, off);
            }
            if ((tid & 63) == 0) { r0[tid >> 6] = v0; r1[tid >> 6] = v1; }
        }
        __syncthreads();
        if (tid == 0) {
            outp[b * 2 + 0] = r0[0] + r0[1] + r0[2] + r0[3] + bout[0];
            outp[b * 2 + 1] = r1[0] + r1[1] + r1[2] + r1[3] + bout[1];
        }
        return;
    }

    __shared__ bf16 hb0[16 * 256];
    __shared__ bf16 hb1[16 * 256];
    __shared__ float pacc[4][4][16][17];
    const int tid  = threadIdx.x;
    const int w    = tid >> 6;
    const int lane = tid & 63;
    const int lr   = lane & 15;
    const int q    = lane >> 4;
    const int bm   = blockIdx.x & 15;
    const int bd   = blockIdx.x >> 4;       // 0..3
    const int kh   = w >> 2;                // K-half
    const int ct   = w & 3;                 // col tile
    const int dg   = bd * 64 + ct * 16 + lr;

    // ---- loop-invariant Whh fragments for this K-half: 64 VGPR ----
    f32x4 wfr[4][4];
#pragma unroll
    for (int g = 0; g < 4; ++g) {
        const bf16* brow = Whhb + (size_t)(g * 256 + dg) * Dd + kh * 128 + q * 8;
#pragma unroll
        for (int kc = 0; kc < 4; ++kc)
            wfr[g][kc] = *(const f32x4*)(brow + kc * 32);
    }

    // gate-preact pointers (kh=0 lanes): rows q*4+r, col dg
    const float* gp[4];
#pragma unroll
    for (int r = 0; r < 4; ++r)
        gp[r] = gates + (size_t)(bm * 16 + q * 4 + r) * (Ss * 1024) + dg;

    // pack/store role (tid < 256): 8 B = 4 cols of one row
    const int xrow = tid >> 4, xc8 = tid & 15;
    const size_t my_base = ((size_t)(bm * 16 + xrow) * Ss) * Dd + bd * 64 + xc8 * 4;
    const int pack_off = xrow * 512 + (((bd * 8 + (xc8 >> 1)) ^ (xrow & 7)) << 4) + (xc8 & 1) * 8;

    // remote-load slots: slot A (all 512 threads), slot B (tid < 256)
    const int pA  = tid >> 8;                         // 0 or 1
    const int pdA = pA + (pA >= bd ? 1 : 0);
    const int pdB = 2 + (2 >= bd ? 1 : 0);
    const int rowA = (tid >> 4) & 15, xqA = tid & 15;
    const size_t gA = ((size_t)(bm * 16 + rowA) * Ss) * Dd + pdA * 64 + xqA * 4;
    const size_t gB = ((size_t)(bm * 16 + xrow) * Ss) * Dd + pdB * 64 + xc8 * 4;
    const int unpA = rowA * 512 + (((pdA * 8 + (xqA >> 1)) ^ (rowA & 7)) << 4) + (xqA & 1) * 8;
    const int unpB = xrow * 512 + (((pdB * 8 + (xc8 >> 1)) ^ (xrow & 7)) << 4) + (xc8 & 1) * 8;
    unsigned* myf = bar + (bm * 4 + bd) * 32;
    unsigned* pfA = bar + (bm * 4 + pdA) * 32;
    unsigned* pfB = bar + (bm * 4 + pdB) * 32;

    // elementwise LDS write offsets (kh=0 lanes): row q*4+r, col dg
    int ew_off[4];
#pragma unroll
    for (int r = 0; r < 4; ++r) {
        const int row = q * 4 + r;
        ew_off[r] = row * 512 + (((dg >> 3) ^ (row & 7)) << 4) + (dg & 7) * 2;
    }

    float c[4] = {0.f, 0.f, 0.f, 0.f};
    float gaA[4][4], gaB[4][4];   // [gate][r], double-buffered preacts
    if (kh == 0) {
#pragma unroll
        for (int r = 0; r < 4; ++r)
#pragma unroll
            for (int g = 0; g < 4; ++g) gaA[g][r] = gp[r][g * 256];
    }

#define STEP(T, GACUR, GANEXT, RD, WR, FIRST)                                   \
    {                                                                           \
        f32x4 acc[4];                                                           \
        _Pragma("unroll")                                                       \
        for (int g = 0; g < 4; ++g) acc[g] = (f32x4){0.f, 0.f, 0.f, 0.f};       \
        if (!(FIRST)) {                                                         \
            bf16x8 af[4];                                                       \
            _Pragma("unroll")                                                   \
            for (int kc = 0; kc < 4; ++kc)                                      \
                af[kc] = *(const bf16x8*)((const char*)(RD) + lr * 512          \
                         + (((kh * 16 + kc * 4 + q) ^ (lr & 7)) << 4));         \
            _Pragma("unroll")                                                   \
            for (int kc = 0; kc < 4; ++kc)                                      \
                _Pragma("unroll")                                               \
                for (int g = 0; g < 4; ++g)                                     \
                    acc[g] = __builtin_amdgcn_mfma_f32_16x16x32_bf16(           \
                        af[kc], __builtin_bit_cast(bf16x8, wfr[g][kc]),         \
                        acc[g], 0, 0, 0);                                       \
        }                                                                       \
        if (kh == 1) {                                                          \
            _Pragma("unroll")                                                   \
            for (int g = 0; g < 4; ++g)                                         \
                _Pragma("unroll")                                               \
                for (int r = 0; r < 4; ++r)                                     \
                    pacc[ct][g][q * 4 + r][lr] = acc[g][r];                     \
        }                                                                       \
        __syncthreads();  /* Ba: kh1 partials visible */                        \
        if (kh == 0) {                                                          \
            _Pragma("unroll")                                                   \
            for (int r = 0; r < 4; ++r) {                                       \
                float gi = acc[0][r] + pacc[ct][0][q * 4 + r][lr] + GACUR[0][r];\
                float gf = acc[1][r] + pacc[ct][1][q * 4 + r][lr] + GACUR[1][r];\
                float gg = acc[2][r] + pacc[ct][2][q * 4 + r][lr] + GACUR[2][r];\
                float go = acc[3][r] + pacc[ct][3][q * 4 + r][lr] + GACUR[3][r];\
                float ii  = 1.f / (1.f + expf(-gi));                            \
                float ff  = 1.f / (1.f + expf(-gf));                            \
                float g2t = tanhf(gg);                                          \
                float oo  = 1.f / (1.f + expf(-go));                            \
                c[r] = ff * c[r] + ii * g2t;                                    \
                *(bf16*)((char*)(WR) + ew_off[r]) = (bf16)(oo * tanhf(c[r]));   \
            }                                                                   \
        }                                                                       \
        __syncthreads();  /* B1: local h slice in LDS */                        \
        if (tid < 256) {                                                        \
            u64 v = *(const u64*)((const char*)(WR) + pack_off);                \
            __hip_atomic_store((u64*)(rnnb + my_base + (size_t)(T) * Dd), v,    \
                               __ATOMIC_RELAXED, __HIP_MEMORY_SCOPE_AGENT);     \
        }                                                                       \
        if ((T) != Ss - 1) {                                                    \
            __syncthreads();  /* B2: per-wave vmcnt(0) -> stores at LLC */      \
            if (tid == 0)                                                       \
                __hip_atomic_store(myf, (unsigned)((T) + 1),                    \
                                   __ATOMIC_RELAXED, __HIP_MEMORY_SCOPE_AGENT); \
            if (kh == 0) {  /* preact prefetch hides under exchange */          \
                _Pragma("unroll")                                               \
                for (int r = 0; r < 4; ++r)                                     \
                    _Pragma("unroll")                                           \
                    for (int g = 0; g < 4; ++g)                                 \
                        GANEXT[g][r] = gp[r][(size_t)((T) + 1) * 1024 + g * 256];\
            }                                                                   \
            while (__hip_atomic_load(pfA, __ATOMIC_RELAXED,                     \
                                     __HIP_MEMORY_SCOPE_AGENT)                  \
                   < (unsigned)((T) + 1)) {}                                    \
            {                                                                   \
                u64 rv = __hip_atomic_load(                                     \
                    (const u64*)(rnnb + gA + (size_t)(T) * Dd),                 \
                    __ATOMIC_RELAXED, __HIP_MEMORY_SCOPE_AGENT);                \
                *(u64*)((char*)(WR) + unpA) = rv;                               \
            }                                                                   \
            if (tid < 256) {                                                    \
                while (__hip_atomic_load(pfB, __ATOMIC_RELAXED,                 \
                                         __HIP_MEMORY_SCOPE_AGENT)              \
                       < (unsigned)((T) + 1)) {}                                \
                u64 rv = __hip_atomic_load(                                     \
                    (const u64*)(rnnb + gB + (size_t)(T) * Dd),                 \
                    __ATOMIC_RELAXED, __HIP_MEMORY_SCOPE_AGENT);                \
                *(u64*)((char*)(WR) + unpB) = rv;                               \
            }                                                                   \
            __syncthreads();  /* B4: full h_t (local+3 remote) in WR */         \
        }                                                                       \
    }

    for (int t2 = 0; t2 < Ss; t2 += 2) {
        STEP(t2,     gaA, gaB, hb1, hb0, (t2 == 0));
        STEP(t2 + 1, gaB, gaA, hb0, hb1, false);
    }
#undef STEP
}

// ---------------- fused prep: converts + transpose + alpha + EMBED ---------
__global__ __launch_bounds__(256) void prep_kernel(
    const float* __restrict__ Wih, bf16* __restrict__ Wihb,
    const float* __restrict__ Whh, bf16* __restrict__ Whhb,
    const float* __restrict__ Whk, bf16* __restrict__ Whkb,
    const float* __restrict__ W1,  bf16* __restrict__ W1b,
    const float* __restrict__ Wdiff, bf16* __restrict__ WdTb,
    const int* __restrict__ tdiff, float* __restrict__ salpha,
    float* __restrict__ sbeta, unsigned* __restrict__ bar,
    const int* __restrict__ seqs, const float* __restrict__ emb,
    float* __restrict__ x, bf16* __restrict__ xb)
{
    __shared__ float t[32][33];
    __shared__ int idx[4][Cc];
    int bx = blockIdx.x;
    const int tid = threadIdx.x;
    if (bx < 1024) { int i = bx * 256 + tid; Wihb[i] = (bf16)Wih[i]; return; }
    bx -= 1024;
    if (bx < 1024) { int i = bx * 256 + tid; Whhb[i] = (bf16)Whh[i]; return; }
    bx -= 1024;
    if (bx < 256)  { int i = bx * 256 + tid; Whkb[i] = (bf16)Whk[i]; return; }
    bx -= 256;
    if (bx < 128)  { int i = bx * 256 + tid; W1b[i]  = (bf16)W1[i];  return; }
    bx -= 128;
    if (bx < 64) {
        const int c0 = (bx & 7) * 32, r0 = (bx >> 3) * 32;
        const int tx = tid & 31, ty = tid >> 5;
        for (int i = ty; i < 32; i += 8)
            t[i][tx] = Wdiff[(size_t)(r0 + i) * 256 + c0 + tx];
        __syncthreads();
        for (int i = ty; i < 32; i += 8)
            WdTb[(size_t)(c0 + i) * 256 + r0 + tx] = (bf16)t[tx][i];
        return;
    }
    bx -= 64;
    if (bx == 0) {
        // alpha + barrier-flag init
#pragma unroll
        for (int j = 0; j < 8; ++j) bar[tid * 8 + j] = 0u;
        const int tt = tdiff[tid];
        const float step = (0.02f - 1e-4f) / 999.f;
        float prod = 1.f;
        for (int j = 0; j <= tt; ++j) prod *= (1.f - (1e-4f + j * step));
        salpha[tid] = sqrtf(prod);
        sbeta[tid]  = sqrtf(fmaxf(1.f - prod, 0.f));
        return;
    }
    bx -= 1;
    // embed: wave-per-(b,s), float4 gathers (bx in [0,3200))
    const int w = tid >> 6, l = tid & 63;
    const int bs0 = bx * 4;
    if (tid < 4 * Cc) idx[tid / Cc][tid % Cc] = seqs[(size_t)bs0 * Cc + tid];
    __syncthreads();
    f32x4 s = (f32x4){0.f, 0.f, 0.f, 0.f};
#pragma unroll 8
    for (int c = 0; c < Cc; ++c)
        s += *(const f32x4*)(emb + (size_t)idx[w][c] * Dd + l * 4);
    const size_t o = (size_t)(bs0 + w) * Dd + l * 4;
    *(f32x4*)(x + o) = s;
    bf16 b4[4] = {(bf16)s[0], (bf16)s[1], (bf16)s[2], (bf16)s[3]};
    *(u64*)(xb + o) = *(const u64*)b4;
}

// ---------------- tail2: Whk GEMM + H1 GEMM + attn + diffusion + pred + pool
// One block per batch b (256 blocks x 256 threads, ~140 KB LDS arena).
// Phase W : w = rnn[b] @ Whk^T + bhk (M=64pad, N=256, K=256). Epilogue ->
//           wL fp32 + swizzled catL bf16 cols 256.. (identical rounding and
//           MFMA accumulation order to the old wbb path).
// Phase H1: H1 = tanh(cat @ W1^T + b1) (M=64pad, N=64, K=512), A straight
//           from catL; logits (·W2 + b2) fused in the epilogue via 16-lane
//           xor-tree + 4-wave partials; softmax -> saL.
// Then r12's verified phases: aligned (LDS, aliases catL) -> tmpb (swizzled,
// aliases wL) -> pred GEMM -> pred write + gen max + pooled head.
__global__ __launch_bounds__(256) void tail2_kernel(
    const float* __restrict__ x, const bf16* __restrict__ xb,
    const bf16* __restrict__ rnnb,
    const bf16* __restrict__ Whkb, const float* __restrict__ bhk,
    const bf16* __restrict__ W1b, const float* __restrict__ b1,
    const float* __restrict__ W2, const float* __restrict__ b2,
    const float* __restrict__ noise, const float* __restrict__ temb,
    const int* __restrict__ tdiff,
    const float* __restrict__ salpha, const float* __restrict__ sbeta,
    const bf16* __restrict__ WdTb, const float* __restrict__ bdiff,
    const float* __restrict__ Wout, const float* __restrict__ bout,
    float* __restrict__ pred_out, float* __restrict__ noise_out,
    float* __restrict__ outp_gen)
{
    __shared__ __align__(16) char arena[139712];
    bf16*  catL = (bf16*)(arena);                 // 64x512 swizzled (64 KB)
    float* wL   = (float*)(arena + 65536);        // 50x256 fp32 (51.2 KB)
    bf16*  Bs   = (bf16*)(arena + 116736);        // B staging (16 KB)
    bf16*  As   = (bf16*)(arena + 133120);        // A staging (4 KB)
    float* v0L  = (float*)(arena + 137216);       // [64][4] logit partials
    float* v1L  = (float*)(arena + 138240);       // [64][4]
    float* saL  = (float*)(arena + 139264);       // [50][2] softmax coeffs
    float* rr   = (float*)(arena + 139664);       // [2][4] pool partials
    float* alignedL = (float*)(arena);            // alias catL (51.2 KB)
    bf16*  tmpbL    = (bf16*)(arena + 65536);     // alias wL (32 KB)

    const int b    = blockIdx.x;
    const int tid  = threadIdx.x;
    const int wave = tid >> 6;
    const int lane = tid & 63;
    const int lr   = lane & 15;
    const int q    = lane >> 4;
    const int ar   = tid >> 2, ac = tid & 3, sw = ac ^ (ar & 3);

    const float ek  = x[((size_t)b * Ss) * Dd + tid];
    const bf16  xbv = xb[((size_t)b * Ss) * Dd + tid];

    // catL x-part: replicate xb[b,0,:] into cols [0,256) of all 64 rows
    {
        const int chunk = tid >> 3;
        for (int t = 0; t < 64; ++t) {
            const int off = t * 1024 + ((chunk ^ (t & 7)) << 4) + (tid & 7) * 2;
            *(bf16*)((char*)catL + off) = xbv;
        }
    }

    // ---- Phase W: w GEMM (M=64, N=256, K=256) ----
    {
        f32x4 acc[4][4];
#pragma unroll
        for (int i = 0; i < 4; ++i)
#pragma unroll
            for (int j = 0; j < 4; ++j) acc[i][j] = (f32x4){0.f, 0.f, 0.f, 0.f};
        const int wn = wave * 64;
        for (int k0 = 0; k0 < 256; k0 += 32) {
            __syncthreads();
            GL2LDS(rnnb + ((size_t)b * Ss + ar) * Dd + k0 + sw * 8, As + wave * 512);
#pragma unroll
            for (int it = 0; it < 4; ++it)
                GL2LDS(Whkb + (size_t)(it * 64 + ar) * Dd + k0 + sw * 8,
                       Bs + it * 2048 + wave * 512);
            __syncthreads();
            bf16x8 af[4], bfv[4];
#pragma unroll
            for (int fm = 0; fm < 4; ++fm) {
                const int m = fm * 16 + lr;
                af[fm] = *(const bf16x8*)(As + m * 32 + ((q ^ (m & 3)) * 8));
            }
#pragma unroll
            for (int fn = 0; fn < 4; ++fn) {
                const int n = wn + fn * 16 + lr;
                bfv[fn] = *(const bf16x8*)(Bs + n * 32 + ((q ^ (n & 3)) * 8));
            }
#pragma unroll
            for (int fm = 0; fm < 4; ++fm)
#pragma unroll
                for (int fn = 0; fn < 4; ++fn)
                    acc[fm][fn] = __builtin_amdgcn_mfma_f32_16x16x32_bf16(
                        af[fm], bfv[fn], acc[fm][fn], 0, 0, 0);
        }
        // epilogue: wL fp32 + catL bf16 (cols 256..)
#pragma unroll
        for (int fn = 0; fn < 4; ++fn) {
            const int col = wn + fn * 16 + lr;
            const float bb = bhk[col];
#pragma unroll
            for (int fm = 0; fm < 4; ++fm) {
#pragma unroll
                for (int r = 0; r < 4; ++r) {
                    const int row = fm * 16 + q * 4 + r;
                    const float val = acc[fm][fn][r] + bb;
                    if (row < Ss) wL[row * 256 + col] = val;
                    if (row < Ss - 1) {
                        const int chunk = 32 + (col >> 3);
                        const int off = row * 1024 + ((chunk ^ (row & 7)) << 4)
                                        + (col & 7) * 2;
                        *(bf16*)((char*)catL + off) = (bf16)val;
                    }
                }
            }
        }
    }

    // ---- Phase H1: H1 GEMM (M=64, N=64, K=512) + fused logits ----
    {
        f32x4 acc2[4];
#pragma unroll
        for (int i = 0; i < 4; ++i) acc2[i] = (f32x4){0.f, 0.f, 0.f, 0.f};
        const int wn = wave * 16;
        for (int k0 = 0; k0 < 512; k0 += 32) {
            __syncthreads();
            GL2LDS(W1b + (size_t)ar * 512 + k0 + sw * 8, Bs + wave * 512);
            __syncthreads();
            bf16x8 af2[4], bv;
#pragma unroll
            for (int fm = 0; fm < 4; ++fm) {
                const int m = fm * 16 + lr;
                const int off = m * 1024 + ((((k0 >> 3) + q) ^ (m & 7)) << 4);
                af2[fm] = *(const bf16x8*)((const char*)catL + off);
            }
            {
                const int n = wn + lr;
                bv = *(const bf16x8*)(Bs + n * 32 + ((q ^ (n & 3)) * 8));
            }
#pragma unroll
            for (int fm = 0; fm < 4; ++fm)
                acc2[fm] = __builtin_amdgcn_mfma_f32_16x16x32_bf16(
                    af2[fm], bv, acc2[fm], 0, 0, 0);
        }
        // fused logits: tanh -> *W2, 16-lane xor reduce, per-wave partials
        const int col = wn + lr;
        const float b1c = b1[col];
        const float w20 = W2[col], w21 = W2[64 + col];
#pragma unroll
        for (int fm = 0; fm < 4; ++fm) {
#pragma unroll
            for (int r = 0; r < 4; ++r) {
                const int row = fm * 16 + q * 4 + r;
                const float h = tanhf(acc2[fm][r] + b1c);
                float t0 = h * w20, t1 = h * w21;
#pragma unroll
                for (int off = 8; off; off >>= 1) {
                    t0 += __shfl_xor(t0, off);
                    t1 += __shfl_xor(t1, off);
                }
                if (lr == 0) { v0L[row * 4 + wave] = t0; v1L[row * 4 + wave] = t1; }
            }
        }
    }
    __syncthreads();
    if (tid < Ss - 1) {
        const float z0 = v0L[tid * 4] + v0L[tid * 4 + 1] + v0L[tid * 4 + 2]
                       + v0L[tid * 4 + 3] + b2[0];
        const float z1 = v1L[tid * 4] + v1L[tid * 4 + 1] + v1L[tid * 4 + 2]
                       + v1L[tid * 4 + 3] + b2[1];
        const float m = fmaxf(z0, z1);
        const float e0 = expf(z0 - m), e1 = expf(z1 - m);
        const float inv = 1.f / (e0 + e1);
        saL[tid * 2 + 0] = e0 * inv;
        saL[tid * 2 + 1] = e1 * inv;
    }
    __syncthreads();

    // ---- aligned pass (writes catL arena; reads wL) + noise passthrough ----
    for (int s = 0; s < Ss; ++s) {
        float v;
        if (s == 0) v = ek;
        else v = ek * saL[(s - 1) * 2] + wL[(s - 1) * 256 + tid] * saL[(s - 1) * 2 + 1];
        alignedL[s * 256 + tid] = v;
        const size_t i = ((size_t)b * Ss + s) * Dd + tid;
        noise_out[i] = noise[i];
    }
    __syncthreads();   // wL dead only after ALL threads finish aligned

    // ---- tmpb pass (writes wL arena) ----
    {
        const int tt = tdiff[b];
        const float sa_ = salpha[b], sb_ = sbeta[b];
        const float te = temb[(size_t)tt * Dd + tid];
        for (int s = 0; s < Ss; ++s) {
            const size_t i = ((size_t)b * Ss + s) * Dd + tid;
            const float v = alignedL[s * 256 + tid];
            const int off = s * 512 + (((tid >> 3) ^ (s & 7)) << 4) + (tid & 7) * 2;
            *(bf16*)((char*)tmpbL + off) = (bf16)(v * sa_ + noise[i] * sb_ + te);
        }
#pragma unroll
        for (int s = Ss; s < 64; ++s) {
            const int off = s * 512 + (((tid >> 3) ^ (s & 7)) << 4) + (tid & 7) * 2;
            *(bf16*)((char*)tmpbL + off) = (bf16)0.f;
        }
    }

    // ---- pred GEMM (M=64, N=256, K=256) ----
    f32x4 acc[4][4];
#pragma unroll
    for (int i = 0; i < 4; ++i)
#pragma unroll
        for (int j = 0; j < 4; ++j) acc[i][j] = (f32x4){0.f, 0.f, 0.f, 0.f};
    const int wn = wave * 64;
    for (int k0 = 0; k0 < 256; k0 += 32) {
        __syncthreads();
#pragma unroll
        for (int it = 0; it < 4; ++it)
            GL2LDS(WdTb + (size_t)(it * 64 + ar) * 256 + k0 + sw * 8,
                   Bs + it * 2048 + wave * 512);
        __syncthreads();
        bf16x8 af[4], bfv[4];
#pragma unroll
        for (int fm = 0; fm < 4; ++fm) {
            const int m = fm * 16 + lr;
            af[fm] = *(const bf16x8*)((const char*)tmpbL + m * 512
                      + ((((k0 >> 3) + q) ^ (m & 7)) << 4));
        }
#pragma unroll
        for (int fn = 0; fn < 4; ++fn) {
            const int n = wn + fn * 16 + lr;
            bfv[fn] = *(const bf16x8*)(Bs + n * 32 + ((q ^ (n & 3)) * 8));
        }
#pragma unroll
        for (int fm = 0; fm < 4; ++fm)
#pragma unroll
            for (int fn = 0; fn < 4; ++fn)
                acc[fm][fn] = __builtin_amdgcn_mfma_f32_16x16x32_bf16(
                    af[fm], bfv[fn], acc[fm][fn], 0, 0, 0);
    }

    // ---- pred write + gen max + pooled head ----
    float v0 = 0.f, v1 = 0.f;
#pragma unroll
    for (int fn = 0; fn < 4; ++fn) {
        const int col = wn + fn * 16 + lr;
        const float bd_ = bdiff[col];
        float mx = -INFINITY;
#pragma unroll
        for (int fm = 0; fm < 4; ++fm) {
#pragma unroll
            for (int r = 0; r < 4; ++r) {
                const int row = fm * 16 + q * 4 + r;
                if (row < Ss) {
                    const float pred = acc[fm][fn][r] + bd_;
                    const size_t i = ((size_t)b * Ss + row) * Dd + col;
                    pred_out[i] = pred;
                    const float gen = alignedL[row * 256 + col] + noise[i] - pred;
                    mx = fmaxf(mx, gen);
                }
            }
        }
        mx = fmaxf(mx, __shfl_xor(mx, 16));
        mx = fmaxf(mx, __shfl_xor(mx, 32));
        if (q == 0) { v0 += mx * Wout[col]; v1 += mx * Wout[Dd + col]; }
    }
#pragma unroll
    for (int off = 32; off; off >>= 1) { v0 += __shfl_down(v0, off); v1 += __shfl_down(v1, off); }
    if (lane == 0) { rr[wave] = v0; rr[4 + wave] = v1; }
    __syncthreads();
    if (tid == 0) {
        outp_gen[b * 2 + 0] = rr[0] + rr[1] + rr[2] + rr[3] + bout[0];
        outp_gen[b * 2 + 1] = rr[4] + rr[5] + rr[6] + rr[7] + bout[1];
    }
}

// ---------------- host ----------------
extern "C" void kernel_launch(void* const* d_in, const int* in_sizes, int n_in,
                              void* d_out, int out_size, void* d_ws, size_t ws_size,
                              hipStream_t stream)
{
    const int*   seqs  = (const int*)d_in[0];
    const int*   tdiff = (const int*)d_in[5];
    const float* noise = (const float*)d_in[6];
    const float* emb   = (const float*)d_in[7];
    const float* Wih   = (const float*)d_in[8];
    const float* Whh   = (const float*)d_in[9];
    const float* bih   = (const float*)d_in[10];
    const float* bhh   = (const float*)d_in[11];
    const float* Whk   = (const float*)d_in[12];
    const float* bhk   = (const float*)d_in[13];
    const float* W1    = (const float*)d_in[14];
    const float* b1    = (const float*)d_in[15];
    const float* W2    = (const float*)d_in[16];
    const float* b2    = (const float*)d_in[17];
    const float* Wdiff = (const float*)d_in[18];
    const float* bdiff = (const float*)d_in[19];
    const float* temb  = (const float*)d_in[20];
    const float* Wout  = (const float*)d_in[21];
    const float* bout  = (const float*)d_in[22];

    float* outp = (float*)d_out;
    char*  wsb  = (char*)d_ws;

    float* gates   = (float*)(wsb + OFFB_GATES);
    float* x       = (float*)(wsb + OFFB_X);
    bf16*  xb      = (bf16*) (wsb + OFFB_XB);
    bf16*  rnnb    = (bf16*) (wsb + OFFB_RNNB);
    unsigned* bar  = (unsigned*)(wsb + OFFB_BAR);
    bf16*  Wihb    = (bf16*) (wsb + OFFB_WIHB);
    bf16*  Whhb    = (bf16*) (wsb + OFFB_WHHB);
    bf16*  Whkb    = (bf16*) (wsb + OFFB_WHKB);
    bf16*  W1b     = (bf16*) (wsb + OFFB_W1B);
    bf16*  WdTb    = (bf16*) (wsb + OFFB_WDTB);
    float* salpha  = (float*)(wsb + OFFB_SALPHA);
    float* sbeta   = (float*)(wsb + OFFB_SBETA);

    float* pred_out  = outp + 1024;                        // (B,S,D)
    float* noise_out = outp + 1024 + (size_t)Bb * Ss * Dd; // (B,S,D)

    // fused prep: weight converts + transpose + alpha + flags + EMBED
    prep_kernel<<<5697, 256, 0, stream>>>(Wih, Wihb, Whh, Whhb, Whk, Whkb,
                                          W1, W1b, Wdiff, WdTb,
                                          tdiff, salpha, sbeta, bar,
                                          seqs, emb, x, xb);

    // gates_pre = x @ Wih^T + bih + bhh : (12800 x 1024), K=256
    mfma_gemm<128, 128, 0><<<dim3(100, 8), 256, 0, stream>>>(
        xb, 256, Wihb, 256, bih, bhh, gates, 1024, 256);

    // LSTM recurrence (blocks 0..63, r9 exchange) + pool_x overlay (64..319)
    lstm_quad<<<64 + Bb, 512, 0, stream>>>(Whhb, gates, rnnb, bar,
                                           x, Wout, bout, outp);

    // tail2: w GEMM + H1 GEMM + attn + diffusion + pred GEMM + pools + copy
    tail2_kernel<<<Bb, 256, 0, stream>>>(
        x, xb, rnnb, Whkb, bhk, W1b, b1, W2, b2,
        noise, temb, tdiff, salpha, sbeta,
        WdTb, bdiff, Wout, bout, pred_out, noise_out, outp + 512);
}